// Round 6
// baseline (368.421 us; speedup 1.0000x reference)
//
#include <hip/hip_runtime.h>
#include <hip/hip_bf16.h>

// BERT layer: B=8,S=512,H=768,NH=12,DH=64,FF=3072. Inputs fp32, mask int32, out fp32.
// Core: bf16 MFMA, fp32 accum. m97-style GEMM (global_load_lds width-16, unpadded LDS).
// Wo/FF2: split-K=4 + fp32 atomicAdd into residual+bias-preinitialized fp32 buffer.
#define H_DIM 768
#define FF_DIM 3072
#define NHEAD 12
#define DHEAD 64
#define SEQ 512
#define TOK 4096

typedef __bf16 bf16;
using bf16x8 = __attribute__((ext_vector_type(8))) __bf16;
using f32x4  = __attribute__((ext_vector_type(4))) float;

static __device__ __forceinline__ f32x4 mfma16(bf16x8 a, bf16x8 b, f32x4 c) {
  return __builtin_amdgcn_mfma_f32_16x16x32_bf16(a, b, c, 0, 0, 0);
}

static __device__ __forceinline__ void gl2lds16(const bf16* g, bf16* l) {
  __builtin_amdgcn_global_load_lds((const __attribute__((address_space(1))) void*)g,
                                   (__attribute__((address_space(3))) void*)l, 16, 0, 0);
}

// ---------------- fp32 -> bf16 conversion (n divisible by 2048) ----------------
__global__ __launch_bounds__(256) void cvt_k(const float* __restrict__ in, bf16* __restrict__ out, int n) {
  int i = (blockIdx.x * 256 + threadIdx.x) * 8;
  if (i >= n) return;
  float4 a = *(const float4*)(in + i);
  float4 b = *(const float4*)(in + i + 4);
  bf16x8 o;
  o[0] = (bf16)a.x; o[1] = (bf16)a.y; o[2] = (bf16)a.z; o[3] = (bf16)a.w;
  o[4] = (bf16)b.x; o[5] = (bf16)b.y; o[6] = (bf16)b.z; o[7] = (bf16)b.w;
  *(bf16x8*)(out + i) = o;
}

// ---------------- fused transpose+convert: fp32 in[R][C] -> bf16 out[C][R] ----------------
__global__ __launch_bounds__(256) void cvtT_k(const float* __restrict__ in, bf16* __restrict__ out,
                                              int R, int C) {
  __shared__ bf16 tile[32][33];
  int c0 = blockIdx.x * 32, r0 = blockIdx.y * 32;
  int tx = threadIdx.x & 31, ty = threadIdx.x >> 5;  // 32 x 8
  for (int i = 0; i < 32; i += 8) tile[ty + i][tx] = (bf16)in[(size_t)(r0 + ty + i) * C + c0 + tx];
  __syncthreads();
  for (int i = 0; i < 32; i += 8) out[(size_t)(c0 + ty + i) * R + r0 + tx] = tile[tx][ty + i];
}

// ---------------- out[i] = res[i] + bias[col]  (fp32, vectorized x4) ----------------
__global__ __launch_bounds__(256) void initres_k(const float* __restrict__ res,
                                                 const float* __restrict__ bias,
                                                 float* __restrict__ out, int total4, int n4) {
  int i = blockIdx.x * 256 + threadIdx.x;
  if (i >= total4) return;
  float4 r = ((const float4*)res)[i];
  const float* bp = bias + (i % n4) * 4;
  float4 o = {r.x + bp[0], r.y + bp[1], r.z + bp[2], r.w + bp[3]};
  ((float4*)out)[i] = o;
}

// ---------------- GEMM core: 128x128 tile, BK=32, m97-style async staging ----------------
// MODE 0: out = bf16(acc + bias)            (QKV: z selects weight/bias/out set)
// MODE 1: out = bf16(gelu(acc + bias))      (FF1)
// MODE 2: atomicAdd(outF, acc), split-K     (Wo/FF2: z = k-slice)
struct GemmArgs {
  const bf16* A;
  const bf16* W[3];      // transposed weights [N][K]
  const float* bias[3];
  bf16* outB[3];
  float* outF;
  int M, N, K, kSlices;
};

#define BK 32

template <int MODE>
__global__ __launch_bounds__(256) void gemm_gl(GemmArgs args) {
  __shared__ bf16 As[128 * BK];   // [row][32] unpadded (global_load_lds layout)
  __shared__ bf16 Bs[128 * BK];
  int z = blockIdx.z;
  const bf16* A = args.A;
  const bf16* Bt;
  int Kd = args.K, N = args.N;
  int kBeg, kEnd;
  if constexpr (MODE == 2) {
    Bt = args.W[0];
    int ks = Kd / args.kSlices;
    kBeg = z * ks; kEnd = kBeg + ks;
  } else {
    Bt = args.W[z];
    kBeg = 0; kEnd = Kd;
  }
  int m0 = blockIdx.y * 128, n0 = blockIdx.x * 128;
  int t = threadIdx.x;
  int wid = t >> 6, lane = t & 63, quad = lane >> 4, l16 = lane & 15;
  int wm = wid >> 1, wn = wid & 1;

  f32x4 zero4 = {0.0f, 0.0f, 0.0f, 0.0f};
  f32x4 acc[4][4];
#pragma unroll
  for (int mi = 0; mi < 4; mi++)
#pragma unroll
    for (int ni = 0; ni < 4; ni++) acc[mi][ni] = zero4;

  // staging: wave wid owns chunks {2*wid, 2*wid+1}; chunk = 16 rows x 32 cols = 1024 B
  int ch = wid * 2;
  int rA = lane >> 2;            // 0..15 within chunk
  int cE = (lane & 3) * 8;       // elem col within 32
  const bf16* gA0 = A  + (size_t)(m0 + ch * 16 + rA) * Kd + cE;
  const bf16* gA1 = gA0 + (size_t)16 * Kd;
  const bf16* gB0 = Bt + (size_t)(n0 + ch * 16 + rA) * Kd + cE;
  const bf16* gB1 = gB0 + (size_t)16 * Kd;
  bf16* lA0 = As + ch * 512;     // wave-uniform chunk base; HW adds lane*16B
  bf16* lA1 = As + ch * 512 + 512;
  bf16* lB0 = Bs + ch * 512;
  bf16* lB1 = Bs + ch * 512 + 512;

  for (int k0 = kBeg; k0 < kEnd; k0 += BK) {
    __syncthreads();
    gl2lds16(gA0 + k0, lA0);
    gl2lds16(gA1 + k0, lA1);
    gl2lds16(gB0 + k0, lB0);
    gl2lds16(gB1 + k0, lB1);
    __syncthreads();
    bf16x8 af[4], bfr[4];
#pragma unroll
    for (int mi = 0; mi < 4; mi++) af[mi] = *(const bf16x8*)&As[(wm * 64 + mi * 16 + l16) * BK + quad * 8];
#pragma unroll
    for (int ni = 0; ni < 4; ni++) bfr[ni] = *(const bf16x8*)&Bs[(wn * 64 + ni * 16 + l16) * BK + quad * 8];
#pragma unroll
    for (int mi = 0; mi < 4; mi++)
#pragma unroll
      for (int ni = 0; ni < 4; ni++) acc[mi][ni] = mfma16(af[mi], bfr[ni], acc[mi][ni]);
  }

  if constexpr (MODE == 2) {
    float* outF = args.outF;
#pragma unroll
    for (int mi = 0; mi < 4; mi++) {
#pragma unroll
      for (int r = 0; r < 4; r++) {
        int row = m0 + wm * 64 + mi * 16 + quad * 4 + r;  // C/D: row=quad*4+reg
#pragma unroll
        for (int ni = 0; ni < 4; ni++) {
          int col = n0 + wn * 64 + ni * 16 + l16;
          atomicAdd(&outF[(size_t)row * N + col], acc[mi][ni][r]);
        }
      }
    }
  } else {
    const float* bias = args.bias[z];
    bf16* outB = args.outB[z];
    float bv[4];
#pragma unroll
    for (int ni = 0; ni < 4; ni++) bv[ni] = bias[n0 + wn * 64 + ni * 16 + l16];
#pragma unroll
    for (int mi = 0; mi < 4; mi++) {
#pragma unroll
      for (int r = 0; r < 4; r++) {
        int row = m0 + wm * 64 + mi * 16 + quad * 4 + r;
#pragma unroll
        for (int ni = 0; ni < 4; ni++) {
          int col = n0 + wn * 64 + ni * 16 + l16;
          float v = acc[mi][ni][r] + bv[ni];
          if constexpr (MODE == 1) v = 0.5f * v * (1.0f + erff(v * 0.70710678118654752f));
          outB[(size_t)row * N + col] = (bf16)v;
        }
      }
    }
  }
}

// ---------------- attention: flash-style, one block = (b,h) x 64 q-rows ----------------
#define CHK 128
#define LPAD 40
__global__ __launch_bounds__(256) void attn_k(const bf16* __restrict__ Qg, const bf16* __restrict__ Kg,
                                              const bf16* __restrict__ Vg, const int* __restrict__ mask,
                                              bf16* __restrict__ ctx) {
  __shared__ bf16 Ks[CHK][72];
  __shared__ bf16 Vts[DHEAD][CHK + 8];
  __shared__ float maskadd[CHK];
  __shared__ bf16 Ps[4][16][LPAD];
  int bh = blockIdx.y;
  int b = bh / NHEAD, h = bh % NHEAD;
  int q0 = blockIdx.x * 64;
  int t = threadIdx.x;
  int wid = t >> 6, lane = t & 63, quad = lane >> 4, l16 = lane & 15;
  size_t base = (size_t)b * SEQ * H_DIM + (size_t)h * DHEAD;

  int qrow = q0 + wid * 16 + l16;
  bf16x8 qf0 = *(const bf16x8*)(Qg + base + (size_t)qrow * H_DIM + quad * 8);
  bf16x8 qf1 = *(const bf16x8*)(Qg + base + (size_t)qrow * H_DIM + 32 + quad * 8);

  f32x4 zero4 = {0.0f, 0.0f, 0.0f, 0.0f};
  f32x4 o[4];
  float m_i[4], l_i[4];
#pragma unroll
  for (int r = 0; r < 4; r++) { o[r] = zero4; m_i[r] = -1e30f; l_i[r] = 0.0f; }

  for (int c0 = 0; c0 < SEQ; c0 += CHK) {
    __syncthreads();
    {  // stage K chunk: 128 keys x 64 dh
      int row = t >> 1, half = (t & 1) * 32;
      const bf16* g = Kg + base + (size_t)(c0 + row) * H_DIM + half;
      *(bf16x8*)&Ks[row][half]      = *(const bf16x8*)g;
      *(bf16x8*)&Ks[row][half + 8]  = *(const bf16x8*)(g + 8);
      *(bf16x8*)&Ks[row][half + 16] = *(const bf16x8*)(g + 16);
      *(bf16x8*)&Ks[row][half + 24] = *(const bf16x8*)(g + 24);
    }
#pragma unroll
    for (int pass = 0; pass < 4; ++pass) {  // stage V^T chunk
      int s = (t >> 3) + pass * 32, dg = (t & 7) * 8;
      bf16x8 v = *(const bf16x8*)(Vg + base + (size_t)(c0 + s) * H_DIM + dg);
#pragma unroll
      for (int j = 0; j < 8; j++) Vts[dg + j][s] = v[j];
    }
    if (t < CHK) maskadd[t] = (1.0f - (float)mask[b * SEQ + c0 + t]) * -10000.0f;
    __syncthreads();

    for (int kt = 0; kt < CHK; kt += 32) {
      f32x4 s0 = zero4, s1 = zero4;
      bf16x8 k0a = *(const bf16x8*)&Ks[kt + l16][quad * 8];
      bf16x8 k0b = *(const bf16x8*)&Ks[kt + l16][32 + quad * 8];
      bf16x8 k1a = *(const bf16x8*)&Ks[kt + 16 + l16][quad * 8];
      bf16x8 k1b = *(const bf16x8*)&Ks[kt + 16 + l16][32 + quad * 8];
      s0 = mfma16(qf0, k0a, s0); s0 = mfma16(qf1, k0b, s0);
      s1 = mfma16(qf0, k1a, s1); s1 = mfma16(qf1, k1b, s1);
      float add0 = maskadd[kt + l16], add1 = maskadd[kt + 16 + l16];
#pragma unroll
      for (int r = 0; r < 4; r++) {
        float v0 = s0[r] * 0.125f + add0;
        float v1 = s1[r] * 0.125f + add1;
        float mx = fmaxf(v0, v1);
#pragma unroll
        for (int off = 1; off < 16; off <<= 1) mx = fmaxf(mx, __shfl_xor(mx, off));
        float mnew = fmaxf(m_i[r], mx);
        float p0 = __expf(v0 - mnew), p1 = __expf(v1 - mnew);
        float alpha = __expf(m_i[r] - mnew);
        m_i[r] = mnew;
        float ps = p0 + p1;
#pragma unroll
        for (int off = 1; off < 16; off <<= 1) ps += __shfl_xor(ps, off);
        l_i[r] = l_i[r] * alpha + ps;
#pragma unroll
        for (int ni = 0; ni < 4; ni++) o[ni][r] *= alpha;
        Ps[wid][quad * 4 + r][l16]      = (bf16)p0;
        Ps[wid][quad * 4 + r][16 + l16] = (bf16)p1;
      }
      bf16x8 pa = *(const bf16x8*)&Ps[wid][l16][quad * 8];
#pragma unroll
      for (int ni = 0; ni < 4; ni++) {
        bf16x8 vb = *(const bf16x8*)&Vts[ni * 16 + l16][kt + quad * 8];
        o[ni] = mfma16(pa, vb, o[ni]);
      }
    }
  }
#pragma unroll
  for (int r = 0; r < 4; r++) {
    int row = q0 + wid * 16 + quad * 4 + r;
    float inv = 1.0f / l_i[r];
#pragma unroll
    for (int ni = 0; ni < 4; ni++)
      ctx[base + (size_t)row * H_DIM + ni * 16 + l16] = (bf16)(o[ni][r] * inv);
  }
}

// ---------------- LayerNorm over H=768 (fp32 in, fp32 params; bf16/fp32 out) ----------------
__global__ __launch_bounds__(256) void ln_k(const float* __restrict__ in, const float* __restrict__ g,
                                            const float* __restrict__ bta, bf16* __restrict__ outB,
                                            float* __restrict__ outF) {
  int row = blockIdx.x, t = threadIdx.x;
  const float* x = in + (size_t)row * H_DIM;
  float v[3], s = 0.0f, sq = 0.0f;
#pragma unroll
  for (int i = 0; i < 3; i++) { v[i] = x[t + i * 256]; s += v[i]; sq += v[i] * v[i]; }
#pragma unroll
  for (int off = 32; off >= 1; off >>= 1) { s += __shfl_down(s, off); sq += __shfl_down(sq, off); }
  __shared__ float ssum[4], ssq[4], smu, srs;
  int lane = t & 63, w = t >> 6;
  if (lane == 0) { ssum[w] = s; ssq[w] = sq; }
  __syncthreads();
  if (t == 0) {
    float S = ssum[0] + ssum[1] + ssum[2] + ssum[3];
    float Q = ssq[0] + ssq[1] + ssq[2] + ssq[3];
    float mu = S * (1.0f / H_DIM);
    float var = Q * (1.0f / H_DIM) - mu * mu;
    smu = mu;
    srs = rsqrtf(var + 1e-3f);
  }
  __syncthreads();
  float mu = smu, rs = srs;
#pragma unroll
  for (int i = 0; i < 3; i++) {
    int c = t + i * 256;
    float y = (v[i] - mu) * rs * g[c] + bta[c];
    if (outB) outB[(size_t)row * H_DIM + c] = (bf16)y;
    if (outF) outF[(size_t)row * H_DIM + c] = y;
  }
}

extern "C" void kernel_launch(void* const* d_in, const int* in_sizes, int n_in,
                              void* d_out, int out_size, void* d_ws, size_t ws_size,
                              hipStream_t stream) {
  const float* x    = (const float*)d_in[0];
  const int*   mask = (const int*)d_in[1];
  const float* Wq = (const float*)d_in[2];  const float* bq = (const float*)d_in[3];
  const float* Wk = (const float*)d_in[4];  const float* bk = (const float*)d_in[5];
  const float* Wv = (const float*)d_in[6];  const float* bv = (const float*)d_in[7];
  const float* Wo = (const float*)d_in[8];  const float* bo = (const float*)d_in[9];
  const float* ln1g = (const float*)d_in[10]; const float* ln1b = (const float*)d_in[11];
  const float* W1 = (const float*)d_in[12]; const float* b1 = (const float*)d_in[13];
  const float* W2 = (const float*)d_in[14]; const float* b2 = (const float*)d_in[15];
  const float* ln2g = (const float*)d_in[16]; const float* ln2b = (const float*)d_in[17];
  float* out = (float*)d_out;
  (void)ws_size; (void)in_sizes; (void)n_in; (void)out_size;

  // ---- workspace layout with lifetime aliasing; peak ≈ 61.5 MiB ----
  char* w = (char*)d_ws;
  const size_t SZ_TH  = (size_t)TOK * H_DIM * 2;      // 6,291,456  bf16 token x H
  const size_t SZ_W   = (size_t)H_DIM * H_DIM * 2;    // 1,179,648  bf16 HxH weight
  const size_t SZ_WF  = (size_t)H_DIM * FF_DIM * 2;   // 4,718,592  bf16 HxFF weight
  bf16* xB  = (bf16*)(w);                              // dead after QKV
  bf16* WqT = (bf16*)(w + SZ_TH);                      // transposed [N][K]
  bf16* WkT = (bf16*)(w + SZ_TH + SZ_W);
  bf16* WvT = (bf16*)(w + SZ_TH + 2 * SZ_W);
  bf16* WoT = (bf16*)(w + SZ_TH + 3 * SZ_W);           // dead after Wo-proj
  bf16* W1T = (bf16*)(w + SZ_TH + 4 * SZ_W);           // dead after FF1
  bf16* W2T = (bf16*)(w + SZ_TH + 4 * SZ_W + SZ_WF);
  char* pQ  = w + SZ_TH + 4 * SZ_W + 2 * SZ_WF;
  bf16* QB  = (bf16*)(pQ);                             // dead after attn
  bf16* KB  = (bf16*)(pQ + SZ_TH);
  bf16* VB  = (bf16*)(pQ + 2 * SZ_TH);
  bf16* CTX = (bf16*)(pQ + 3 * SZ_TH);                 // dead after Wo
  float* PRE1 = (float*)(pQ + 4 * SZ_TH);              // dead after LN1
  bf16* H1   = QB;                                     // alias QB
  float* H1F = (float*)(pQ + SZ_TH);                   // alias KB+VB
  bf16* FFA  = CTX;                                    // CTX + PRE1 + 6.3M
  float* PRE2 = (float*)(w);                           // aliases xB+WqT..WoT+part W1T (all dead by FF2)

  dim3 tb(256);

  // conversions: x (straight), weights (transpose+convert to [N][K])
  cvt_k<<<(TOK * H_DIM) / 2048, tb, 0, stream>>>(x, xB, TOK * H_DIM);
  cvtT_k<<<dim3(24, 24), tb, 0, stream>>>(Wq, WqT, H_DIM, H_DIM);
  cvtT_k<<<dim3(24, 24), tb, 0, stream>>>(Wk, WkT, H_DIM, H_DIM);
  cvtT_k<<<dim3(24, 24), tb, 0, stream>>>(Wv, WvT, H_DIM, H_DIM);
  cvtT_k<<<dim3(24, 24), tb, 0, stream>>>(Wo, WoT, H_DIM, H_DIM);
  cvtT_k<<<dim3(96, 24), tb, 0, stream>>>(W1, W1T, H_DIM, FF_DIM);
  cvtT_k<<<dim3(24, 96), tb, 0, stream>>>(W2, W2T, FF_DIM, H_DIM);

  // fused QKV projection: MODE 0, grid 6x32x3 = 576 blocks
  GemmArgs ga = {};
  ga.A = xB; ga.M = TOK; ga.N = H_DIM; ga.K = H_DIM; ga.kSlices = 1;
  ga.W[0] = WqT; ga.W[1] = WkT; ga.W[2] = WvT;
  ga.bias[0] = bq; ga.bias[1] = bk; ga.bias[2] = bv;
  ga.outB[0] = QB; ga.outB[1] = KB; ga.outB[2] = VB;
  gemm_gl<0><<<dim3(H_DIM / 128, TOK / 128, 3), tb, 0, stream>>>(ga);

  // attention: 768 blocks
  attn_k<<<dim3(SEQ / 64, 8 * NHEAD), tb, 0, stream>>>(QB, KB, VB, mask, CTX);

  // PRE1 = x + bo; Wo-proj split-K=4 atomically accumulates; then LN1
  initres_k<<<(TOK * H_DIM / 4 + 255) / 256, tb, 0, stream>>>(x, bo, PRE1, TOK * H_DIM / 4, H_DIM / 4);
  GemmArgs go = {};
  go.A = CTX; go.M = TOK; go.N = H_DIM; go.K = H_DIM; go.kSlices = 4;
  go.W[0] = WoT; go.outF = PRE1;
  gemm_gl<2><<<dim3(H_DIM / 128, TOK / 128, 4), tb, 0, stream>>>(go);
  ln_k<<<TOK, tb, 0, stream>>>(PRE1, ln1g, ln1b, H1, H1F);

  // FF1 + GELU: MODE 1, grid 24x32 = 768 blocks
  GemmArgs g1 = {};
  g1.A = H1; g1.M = TOK; g1.N = FF_DIM; g1.K = H_DIM; g1.kSlices = 1;
  g1.W[0] = W1T; g1.bias[0] = b1; g1.outB[0] = FFA;
  gemm_gl<1><<<dim3(FF_DIM / 128, TOK / 128, 1), tb, 0, stream>>>(g1);

  // PRE2 = h1 + b2; FF2 split-K=4 atomically accumulates; then LN2 -> out
  initres_k<<<(TOK * H_DIM / 4 + 255) / 256, tb, 0, stream>>>(H1F, b2, PRE2, TOK * H_DIM / 4, H_DIM / 4);
  GemmArgs g2 = {};
  g2.A = FFA; g2.M = TOK; g2.N = H_DIM; g2.K = FF_DIM; g2.kSlices = 4;
  g2.W[0] = W2T; g2.outF = PRE2;
  gemm_gl<2><<<dim3(H_DIM / 128, TOK / 128, 4), tb, 0, stream>>>(g2);
  ln_k<<<TOK, tb, 0, stream>>>(PRE2, ln2g, ln2b, nullptr, out);
}

// Round 7
// 309.484 us; speedup vs baseline: 1.1904x; 1.1904x over previous
//
#include <hip/hip_runtime.h>
#include <hip/hip_bf16.h>

// BERT layer: B=8,S=512,H=768,NH=12,DH=64,FF=3072. Inputs fp32, mask int32, out fp32.
// bf16 MFMA + fp32 accum. m97-style staging (global_load_lds w16). XCD-swizzled 1-D grid.
// Wo/FF2: split-K=2, fp32 partial tiles + fused reduce+residual+LayerNorm.
#define H_DIM 768
#define FF_DIM 3072
#define NHEAD 12
#define DHEAD 64
#define SEQ 512
#define TOK 4096

typedef __bf16 bf16;
using bf16x8 = __attribute__((ext_vector_type(8))) __bf16;
using f32x4  = __attribute__((ext_vector_type(4))) float;

static __device__ __forceinline__ f32x4 mfma16(bf16x8 a, bf16x8 b, f32x4 c) {
  return __builtin_amdgcn_mfma_f32_16x16x32_bf16(a, b, c, 0, 0, 0);
}

static __device__ __forceinline__ void gl2lds16(const bf16* g, bf16* l) {
  __builtin_amdgcn_global_load_lds((const __attribute__((address_space(1))) void*)g,
                                   (__attribute__((address_space(3))) void*)l, 16, 0, 0);
}

// ---------------- fp32 -> bf16 conversion (n divisible by 2048) ----------------
__global__ __launch_bounds__(256) void cvt_k(const float* __restrict__ in, bf16* __restrict__ out, int n) {
  int i = (blockIdx.x * 256 + threadIdx.x) * 8;
  if (i >= n) return;
  float4 a = *(const float4*)(in + i);
  float4 b = *(const float4*)(in + i + 4);
  bf16x8 o;
  o[0] = (bf16)a.x; o[1] = (bf16)a.y; o[2] = (bf16)a.z; o[3] = (bf16)a.w;
  o[4] = (bf16)b.x; o[5] = (bf16)b.y; o[6] = (bf16)b.z; o[7] = (bf16)b.w;
  *(bf16x8*)(out + i) = o;
}

// ---------------- fused transpose+convert: fp32 in[R][C] -> bf16 out[C][R] ----------------
__global__ __launch_bounds__(256) void cvtT_k(const float* __restrict__ in, bf16* __restrict__ out,
                                              int R, int C) {
  __shared__ bf16 tile[32][33];
  int c0 = blockIdx.x * 32, r0 = blockIdx.y * 32;
  int tx = threadIdx.x & 31, ty = threadIdx.x >> 5;  // 32 x 8
  for (int i = 0; i < 32; i += 8) tile[ty + i][tx] = (bf16)in[(size_t)(r0 + ty + i) * C + c0 + tx];
  __syncthreads();
  for (int i = 0; i < 32; i += 8) out[(size_t)(c0 + ty + i) * R + r0 + tx] = tile[tx][ty + i];
}

// ---------------- GEMM: 128x128 tile, BK=32, async staging, XCD-swizzled 1-D grid ----------
// MODE 0: out = bf16(acc + bias)        MODE 1: out = bf16(gelu(acc + bias))
// MODE 2: outP[z][row*N+col] = acc      (split-K partial, plain fp32 stores)
struct GemmArgs {
  const bf16* A;
  const bf16* W[3];      // transposed weights [N][K]
  const float* bias[3];
  bf16* outB[3];
  float* outP[2];
  int N, K, nx, ry, kSlices;  // ry = (M/128)/8 rows per XCD
};

#define BK 32

template <int MODE>
__global__ __launch_bounds__(256) void gemm_x(GemmArgs args) {
  __shared__ bf16 As[128 * BK];   // [row][32] unpadded (global_load_lds layout)
  __shared__ bf16 Bs[128 * BK];
  // XCD-aware decode: xcd = bid%8; within XCD iterate by fastest (A-rows L2-resident)
  int bid = blockIdx.x;
  int xcd = bid & 7, tt = bid >> 3;
  int ry = args.ry;
  int by = xcd * ry + (tt % ry);
  int rest = tt / ry;
  int bx = rest % args.nx;
  int z = rest / args.nx;

  const bf16* A = args.A;
  const bf16* Bt;
  int Kd = args.K, N = args.N;
  int kBeg, kEnd;
  if constexpr (MODE == 2) {
    Bt = args.W[0];
    int ks = Kd / args.kSlices;
    kBeg = z * ks; kEnd = kBeg + ks;
  } else {
    Bt = args.W[z];
    kBeg = 0; kEnd = Kd;
  }
  int m0 = by * 128, n0 = bx * 128;
  int t = threadIdx.x;
  int wid = t >> 6, lane = t & 63, quad = lane >> 4, l16 = lane & 15;
  int wm = wid >> 1, wn = wid & 1;

  f32x4 zero4 = {0.0f, 0.0f, 0.0f, 0.0f};
  f32x4 acc[4][4];
#pragma unroll
  for (int mi = 0; mi < 4; mi++)
#pragma unroll
    for (int ni = 0; ni < 4; ni++) acc[mi][ni] = zero4;

  // staging: wave wid owns chunks {2*wid, 2*wid+1}; chunk = 16 rows x 32 cols
  int ch = wid * 2;
  int rA = lane >> 2;
  int cE = (lane & 3) * 8;
  const bf16* gA0 = A  + (size_t)(m0 + ch * 16 + rA) * Kd + cE;
  const bf16* gA1 = gA0 + (size_t)16 * Kd;
  const bf16* gB0 = Bt + (size_t)(n0 + ch * 16 + rA) * Kd + cE;
  const bf16* gB1 = gB0 + (size_t)16 * Kd;
  bf16* lA0 = As + ch * 512;
  bf16* lA1 = As + ch * 512 + 512;
  bf16* lB0 = Bs + ch * 512;
  bf16* lB1 = Bs + ch * 512 + 512;

  for (int k0 = kBeg; k0 < kEnd; k0 += BK) {
    __syncthreads();
    gl2lds16(gA0 + k0, lA0);
    gl2lds16(gA1 + k0, lA1);
    gl2lds16(gB0 + k0, lB0);
    gl2lds16(gB1 + k0, lB1);
    __syncthreads();
    bf16x8 af[4], bfr[4];
#pragma unroll
    for (int mi = 0; mi < 4; mi++) af[mi] = *(const bf16x8*)&As[(wm * 64 + mi * 16 + l16) * BK + quad * 8];
#pragma unroll
    for (int ni = 0; ni < 4; ni++) bfr[ni] = *(const bf16x8*)&Bs[(wn * 64 + ni * 16 + l16) * BK + quad * 8];
#pragma unroll
    for (int mi = 0; mi < 4; mi++)
#pragma unroll
      for (int ni = 0; ni < 4; ni++) acc[mi][ni] = mfma16(af[mi], bfr[ni], acc[mi][ni]);
  }

  if constexpr (MODE == 2) {
    float* outP = args.outP[z];
#pragma unroll
    for (int mi = 0; mi < 4; mi++) {
#pragma unroll
      for (int r = 0; r < 4; r++) {
        int row = m0 + wm * 64 + mi * 16 + quad * 4 + r;  // C/D: row=quad*4+reg (m89-verified)
#pragma unroll
        for (int ni = 0; ni < 4; ni++) {
          int col = n0 + wn * 64 + ni * 16 + l16;
          outP[(size_t)row * N + col] = acc[mi][ni][r];
        }
      }
    }
  } else {
    const float* bias = args.bias[z];
    bf16* outB = args.outB[z];
    float bv[4];
#pragma unroll
    for (int ni = 0; ni < 4; ni++) bv[ni] = bias[n0 + wn * 64 + ni * 16 + l16];
#pragma unroll
    for (int mi = 0; mi < 4; mi++) {
#pragma unroll
      for (int r = 0; r < 4; r++) {
        int row = m0 + wm * 64 + mi * 16 + quad * 4 + r;
#pragma unroll
        for (int ni = 0; ni < 4; ni++) {
          int col = n0 + wn * 64 + ni * 16 + l16;
          float v = acc[mi][ni][r] + bv[ni];
          if constexpr (MODE == 1) v = 0.5f * v * (1.0f + erff(v * 0.70710678118654752f));
          outB[(size_t)row * N + col] = (bf16)v;
        }
      }
    }
  }
}

// ---------------- attention: flash-style, one block = (b,h) x 64 q-rows ----------------
#define CHK 128
#define LPAD 40
__global__ __launch_bounds__(256) void attn_k(const bf16* __restrict__ Qg, const bf16* __restrict__ Kg,
                                              const bf16* __restrict__ Vg, const int* __restrict__ mask,
                                              bf16* __restrict__ ctx) {
  __shared__ bf16 Ks[CHK][72];
  __shared__ bf16 Vts[DHEAD][CHK + 8];
  __shared__ float maskadd[CHK];
  __shared__ bf16 Ps[4][16][LPAD];
  int bh = blockIdx.y;
  int b = bh / NHEAD, h = bh % NHEAD;
  int q0 = blockIdx.x * 64;
  int t = threadIdx.x;
  int wid = t >> 6, lane = t & 63, quad = lane >> 4, l16 = lane & 15;
  size_t base = (size_t)b * SEQ * H_DIM + (size_t)h * DHEAD;

  int qrow = q0 + wid * 16 + l16;
  bf16x8 qf0 = *(const bf16x8*)(Qg + base + (size_t)qrow * H_DIM + quad * 8);
  bf16x8 qf1 = *(const bf16x8*)(Qg + base + (size_t)qrow * H_DIM + 32 + quad * 8);

  f32x4 zero4 = {0.0f, 0.0f, 0.0f, 0.0f};
  f32x4 o[4];
  float m_i[4], l_i[4];
#pragma unroll
  for (int r = 0; r < 4; r++) { o[r] = zero4; m_i[r] = -1e30f; l_i[r] = 0.0f; }

  for (int c0 = 0; c0 < SEQ; c0 += CHK) {
    __syncthreads();
    {
      int row = t >> 1, half = (t & 1) * 32;
      const bf16* g = Kg + base + (size_t)(c0 + row) * H_DIM + half;
      *(bf16x8*)&Ks[row][half]      = *(const bf16x8*)g;
      *(bf16x8*)&Ks[row][half + 8]  = *(const bf16x8*)(g + 8);
      *(bf16x8*)&Ks[row][half + 16] = *(const bf16x8*)(g + 16);
      *(bf16x8*)&Ks[row][half + 24] = *(const bf16x8*)(g + 24);
    }
#pragma unroll
    for (int pass = 0; pass < 4; ++pass) {
      int s = (t >> 3) + pass * 32, dg = (t & 7) * 8;
      bf16x8 v = *(const bf16x8*)(Vg + base + (size_t)(c0 + s) * H_DIM + dg);
#pragma unroll
      for (int j = 0; j < 8; j++) Vts[dg + j][s] = v[j];
    }
    if (t < CHK) maskadd[t] = (1.0f - (float)mask[b * SEQ + c0 + t]) * -10000.0f;
    __syncthreads();

    for (int kt = 0; kt < CHK; kt += 32) {
      f32x4 s0 = zero4, s1 = zero4;
      bf16x8 k0a = *(const bf16x8*)&Ks[kt + l16][quad * 8];
      bf16x8 k0b = *(const bf16x8*)&Ks[kt + l16][32 + quad * 8];
      bf16x8 k1a = *(const bf16x8*)&Ks[kt + 16 + l16][quad * 8];
      bf16x8 k1b = *(const bf16x8*)&Ks[kt + 16 + l16][32 + quad * 8];
      s0 = mfma16(qf0, k0a, s0); s0 = mfma16(qf1, k0b, s0);
      s1 = mfma16(qf0, k1a, s1); s1 = mfma16(qf1, k1b, s1);
      float add0 = maskadd[kt + l16], add1 = maskadd[kt + 16 + l16];
#pragma unroll
      for (int r = 0; r < 4; r++) {
        float v0 = s0[r] * 0.125f + add0;
        float v1 = s1[r] * 0.125f + add1;
        float mx = fmaxf(v0, v1);
#pragma unroll
        for (int off = 1; off < 16; off <<= 1) mx = fmaxf(mx, __shfl_xor(mx, off));
        float mnew = fmaxf(m_i[r], mx);
        float p0 = __expf(v0 - mnew), p1 = __expf(v1 - mnew);
        float alpha = __expf(m_i[r] - mnew);
        m_i[r] = mnew;
        float ps = p0 + p1;
#pragma unroll
        for (int off = 1; off < 16; off <<= 1) ps += __shfl_xor(ps, off);
        l_i[r] = l_i[r] * alpha + ps;
#pragma unroll
        for (int ni = 0; ni < 4; ni++) o[ni][r] *= alpha;
        Ps[wid][quad * 4 + r][l16]      = (bf16)p0;
        Ps[wid][quad * 4 + r][16 + l16] = (bf16)p1;
      }
      bf16x8 pa = *(const bf16x8*)&Ps[wid][l16][quad * 8];
#pragma unroll
      for (int ni = 0; ni < 4; ni++) {
        bf16x8 vb = *(const bf16x8*)&Vts[ni * 16 + l16][kt + quad * 8];
        o[ni] = mfma16(pa, vb, o[ni]);
      }
    }
  }
#pragma unroll
  for (int r = 0; r < 4; r++) {
    int row = q0 + wid * 16 + quad * 4 + r;
    float inv = 1.0f / l_i[r];
#pragma unroll
    for (int ni = 0; ni < 4; ni++)
      ctx[base + (size_t)row * H_DIM + ni * 16 + l16] = (bf16)(o[ni][r] * inv);
  }
}

// --------- fused reduce(2 partials) + residual + bias + LayerNorm over H=768 ----------
__global__ __launch_bounds__(256) void redln_k(const float* __restrict__ p0, const float* __restrict__ p1,
                                               const float* __restrict__ resF, const bf16* __restrict__ resB,
                                               const float* __restrict__ bias,
                                               const float* __restrict__ g, const float* __restrict__ bta,
                                               bf16* __restrict__ outB, float* __restrict__ outF) {
  int row = blockIdx.x, t = threadIdx.x;
  size_t base = (size_t)row * H_DIM;
  float v[3], s = 0.0f, sq = 0.0f;
#pragma unroll
  for (int i = 0; i < 3; i++) {
    int c = t + i * 256;
    float r = resF ? resF[base + c] : (float)resB[base + c];
    float x = p0[base + c] + p1[base + c] + bias[c] + r;
    v[i] = x; s += x; sq += x * x;
  }
#pragma unroll
  for (int off = 32; off >= 1; off >>= 1) { s += __shfl_down(s, off); sq += __shfl_down(sq, off); }
  __shared__ float ssum[4], ssq[4], smu, srs;
  int lane = t & 63, w = t >> 6;
  if (lane == 0) { ssum[w] = s; ssq[w] = sq; }
  __syncthreads();
  if (t == 0) {
    float S = ssum[0] + ssum[1] + ssum[2] + ssum[3];
    float Q = ssq[0] + ssq[1] + ssq[2] + ssq[3];
    float mu = S * (1.0f / H_DIM);
    float var = Q * (1.0f / H_DIM) - mu * mu;
    smu = mu;
    srs = rsqrtf(var + 1e-3f);
  }
  __syncthreads();
  float mu = smu, rs = srs;
#pragma unroll
  for (int i = 0; i < 3; i++) {
    int c = t + i * 256;
    float y = (v[i] - mu) * rs * g[c] + bta[c];
    if (outB) outB[base + c] = (bf16)y;
    if (outF) outF[base + c] = y;
  }
}

extern "C" void kernel_launch(void* const* d_in, const int* in_sizes, int n_in,
                              void* d_out, int out_size, void* d_ws, size_t ws_size,
                              hipStream_t stream) {
  const float* x    = (const float*)d_in[0];
  const int*   mask = (const int*)d_in[1];
  const float* Wq = (const float*)d_in[2];  const float* bq = (const float*)d_in[3];
  const float* Wk = (const float*)d_in[4];  const float* bk = (const float*)d_in[5];
  const float* Wv = (const float*)d_in[6];  const float* bv = (const float*)d_in[7];
  const float* Wo = (const float*)d_in[8];  const float* bo = (const float*)d_in[9];
  const float* ln1g = (const float*)d_in[10]; const float* ln1b = (const float*)d_in[11];
  const float* W1 = (const float*)d_in[12]; const float* b1 = (const float*)d_in[13];
  const float* W2 = (const float*)d_in[14]; const float* b2 = (const float*)d_in[15];
  const float* ln2g = (const float*)d_in[16]; const float* ln2b = (const float*)d_in[17];
  float* out = (float*)d_out;
  (void)ws_size; (void)in_sizes; (void)n_in; (void)out_size;

  // ---- workspace: exact lifetime aliasing, peak 61,341,696 B ----
  char* w = (char*)d_ws;
  const size_t SZ_TH  = 6291456;    // bf16 TOK x H
  const size_t SZ_THF = 12582912;   // fp32 TOK x H
  const size_t SZ_W   = 1179648;    // bf16 H x H
  const size_t SZ_WF  = 4718592;    // bf16 H x FF
  bf16* xB   = (bf16*)(w);                        // [0, 6.29M)  dead after QKV
  bf16* QB   = (bf16*)(w + SZ_TH);                // dead after attn
  bf16* KB   = (bf16*)(w + 2 * SZ_TH);
  bf16* VB   = (bf16*)(w + 3 * SZ_TH);
  float* P1s0 = (float*)(w);                      // [0, 12.58M)   over xB+QB (dead)
  float* P1s1 = (float*)(w + SZ_THF);             // [12.58, 25.17M) over KB+VB (dead)
  bf16* FFA  = (bf16*)(w);                        // [0, 25.17M)  over P1 (dead after redLN1)
  bf16* CTX  = (bf16*)(w + 4 * SZ_TH);            // [25.17, 31.46M) dead after Wo-gemm
  bf16* H1   = CTX;                               // redLN1 out; alive till redLN2
  bf16* WqT  = (bf16*)(w + 5 * SZ_TH);            // [31.46M ...) dead after QKV
  bf16* WkT  = (bf16*)(w + 5 * SZ_TH + SZ_W);
  bf16* WvT  = (bf16*)(w + 5 * SZ_TH + 2 * SZ_W);
  bf16* WoT  = (bf16*)(w + 5 * SZ_TH + 3 * SZ_W); // dead after Wo-gemm
  bf16* W1T  = (bf16*)(w + 5 * SZ_TH + 4 * SZ_W); // [36.18, 40.89M) dead after FF1
  float* P2s0 = (float*)(w + 5 * SZ_TH);          // [31.46, 44.04M) over WqT..W1T (dead by FF2)
  float* P2s1 = (float*)(w + 5 * SZ_TH + SZ_THF); // [44.04, 56.62M) free region
  bf16* W2T  = (bf16*)(w + 5 * SZ_TH + 2 * SZ_THF); // [56.62, 61.34M) alive till FF2-gemm

  dim3 tb(256);

  // conversions: x straight; weights transpose+convert to [N][K]
  cvt_k<<<(TOK * H_DIM) / 2048, tb, 0, stream>>>(x, xB, TOK * H_DIM);
  cvtT_k<<<dim3(24, 24), tb, 0, stream>>>(Wq, WqT, H_DIM, H_DIM);
  cvtT_k<<<dim3(24, 24), tb, 0, stream>>>(Wk, WkT, H_DIM, H_DIM);
  cvtT_k<<<dim3(24, 24), tb, 0, stream>>>(Wv, WvT, H_DIM, H_DIM);
  cvtT_k<<<dim3(24, 24), tb, 0, stream>>>(Wo, WoT, H_DIM, H_DIM);
  cvtT_k<<<dim3(96, 24), tb, 0, stream>>>(W1, W1T, H_DIM, FF_DIM);
  cvtT_k<<<dim3(24, 96), tb, 0, stream>>>(W2, W2T, FF_DIM, H_DIM);

  // QKV: MODE 0, 1-D grid 6*32*3 = 576, XCD-swizzled (ry = 32/8 = 4)
  GemmArgs ga = {};
  ga.A = xB; ga.N = H_DIM; ga.K = H_DIM; ga.nx = 6; ga.ry = 4; ga.kSlices = 1;
  ga.W[0] = WqT; ga.W[1] = WkT; ga.W[2] = WvT;
  ga.bias[0] = bq; ga.bias[1] = bk; ga.bias[2] = bv;
  ga.outB[0] = QB; ga.outB[1] = KB; ga.outB[2] = VB;
  gemm_x<0><<<576, tb, 0, stream>>>(ga);

  // attention
  attn_k<<<dim3(SEQ / 64, 8 * NHEAD), tb, 0, stream>>>(QB, KB, VB, mask, CTX);

  // Wo-proj: MODE 2 split-K=2, grid 6*32*2 = 384
  GemmArgs go = {};
  go.A = CTX; go.N = H_DIM; go.K = H_DIM; go.nx = 6; go.ry = 4; go.kSlices = 2;
  go.W[0] = WoT; go.outP[0] = P1s0; go.outP[1] = P1s1;
  gemm_x<2><<<384, tb, 0, stream>>>(go);

  // reduce + residual(x) + bias(bo) + LN1 -> H1 (bf16)
  redln_k<<<TOK, tb, 0, stream>>>(P1s0, P1s1, x, nullptr, bo, ln1g, ln1b, H1, nullptr);

  // FF1 + GELU: MODE 1, grid 24*32 = 768
  GemmArgs g1 = {};
  g1.A = H1; g1.N = FF_DIM; g1.K = H_DIM; g1.nx = 24; g1.ry = 4; g1.kSlices = 1;
  g1.W[0] = W1T; g1.bias[0] = b1; g1.outB[0] = FFA;
  gemm_x<1><<<768, tb, 0, stream>>>(g1);

  // FF2: MODE 2 split-K=2, grid 384
  GemmArgs g2 = {};
  g2.A = FFA; g2.N = H_DIM; g2.K = FF_DIM; g2.nx = 6; g2.ry = 4; g2.kSlices = 2;
  g2.W[0] = W2T; g2.outP[0] = P2s0; g2.outP[1] = P2s1;
  gemm_x<2><<<384, tb, 0, stream>>>(g2);

  // reduce + residual(H1 bf16) + bias(b2) + LN2 -> out (fp32)
  redln_k<<<TOK, tb, 0, stream>>>(P2s0, P2s1, nullptr, H1, b2, ln2g, ln2b, nullptr, out);
}

// Round 8
// 286.039 us; speedup vs baseline: 1.2880x; 1.0820x over previous
//
#include <hip/hip_runtime.h>
#include <hip/hip_bf16.h>

// BERT layer: B=8,S=512,H=768,NH=12,DH=64,FF=3072. Inputs fp32, mask int32, out fp32.
// bf16 MFMA + fp32 accum. m97-style GEMM staging, XCD-swizzled grids.
// Wo/FF2: split-K=2 + fused reduce+residual+LayerNorm. Attention: batched-128 softmax.
#define H_DIM 768
#define FF_DIM 3072
#define NHEAD 12
#define DHEAD 64
#define SEQ 512
#define TOK 4096

typedef __bf16 bf16;
using bf16x8 = __attribute__((ext_vector_type(8))) __bf16;
using f32x4  = __attribute__((ext_vector_type(4))) float;

static __device__ __forceinline__ f32x4 mfma16(bf16x8 a, bf16x8 b, f32x4 c) {
  return __builtin_amdgcn_mfma_f32_16x16x32_bf16(a, b, c, 0, 0, 0);
}

static __device__ __forceinline__ void gl2lds16(const bf16* g, bf16* l) {
  __builtin_amdgcn_global_load_lds((const __attribute__((address_space(1))) void*)g,
                                   (__attribute__((address_space(3))) void*)l, 16, 0, 0);
}

// ---------------- fp32 -> bf16 conversion (n divisible by 2048) ----------------
__global__ __launch_bounds__(256) void cvt_k(const float* __restrict__ in, bf16* __restrict__ out, int n) {
  int i = (blockIdx.x * 256 + threadIdx.x) * 8;
  if (i >= n) return;
  float4 a = *(const float4*)(in + i);
  float4 b = *(const float4*)(in + i + 4);
  bf16x8 o;
  o[0] = (bf16)a.x; o[1] = (bf16)a.y; o[2] = (bf16)a.z; o[3] = (bf16)a.w;
  o[4] = (bf16)b.x; o[5] = (bf16)b.y; o[6] = (bf16)b.z; o[7] = (bf16)b.w;
  *(bf16x8*)(out + i) = o;
}

// ------- fused transpose+convert: fp32 in[R][C] -> bf16 out[C][R]; z selects tensor -------
struct CvtTArgs { const float* in[4]; bf16* out[4]; };
__global__ __launch_bounds__(256) void cvtT_k(CvtTArgs args, int R, int C) {
  __shared__ bf16 tile[32][33];
  const float* in = args.in[blockIdx.z];
  bf16* out = args.out[blockIdx.z];
  int c0 = blockIdx.x * 32, r0 = blockIdx.y * 32;
  int tx = threadIdx.x & 31, ty = threadIdx.x >> 5;  // 32 x 8
  for (int i = 0; i < 32; i += 8) tile[ty + i][tx] = (bf16)in[(size_t)(r0 + ty + i) * C + c0 + tx];
  __syncthreads();
  for (int i = 0; i < 32; i += 8) out[(size_t)(c0 + ty + i) * R + r0 + tx] = tile[tx][ty + i];
}

// ---------------- GEMM: 128x128 tile, BK=32, async staging, XCD-swizzled 1-D grid ----------
// MODE 0: out = bf16(acc + bias)        MODE 1: out = bf16(gelu(acc + bias))
// MODE 2: outP[z][row*N+col] = acc      (split-K partial, plain fp32 stores)
struct GemmArgs {
  const bf16* A;
  const bf16* W[3];      // transposed weights [N][K]
  const float* bias[3];
  bf16* outB[3];
  float* outP[2];
  int N, K, nx, ry, kSlices;  // ry = (M/128)/8 rows per XCD
};

#define BK 32

template <int MODE>
__global__ __launch_bounds__(256) void gemm_x(GemmArgs args) {
  __shared__ bf16 As[128 * BK];   // [row][32] unpadded (global_load_lds layout)
  __shared__ bf16 Bs[128 * BK];
  int bid = blockIdx.x;
  int xcd = bid & 7, tt = bid >> 3;
  int ry = args.ry;
  int by = xcd * ry + (tt % ry);
  int rest = tt / ry;
  int bx = rest % args.nx;
  int z = rest / args.nx;

  const bf16* A = args.A;
  const bf16* Bt;
  int Kd = args.K, N = args.N;
  int kBeg, kEnd;
  if constexpr (MODE == 2) {
    Bt = args.W[0];
    int ks = Kd / args.kSlices;
    kBeg = z * ks; kEnd = kBeg + ks;
  } else {
    Bt = args.W[z];
    kBeg = 0; kEnd = Kd;
  }
  int m0 = by * 128, n0 = bx * 128;
  int t = threadIdx.x;
  int wid = t >> 6, lane = t & 63, quad = lane >> 4, l16 = lane & 15;
  int wm = wid >> 1, wn = wid & 1;

  f32x4 zero4 = {0.0f, 0.0f, 0.0f, 0.0f};
  f32x4 acc[4][4];
#pragma unroll
  for (int mi = 0; mi < 4; mi++)
#pragma unroll
    for (int ni = 0; ni < 4; ni++) acc[mi][ni] = zero4;

  int ch = wid * 2;
  int rA = lane >> 2;
  int cE = (lane & 3) * 8;
  const bf16* gA0 = A  + (size_t)(m0 + ch * 16 + rA) * Kd + cE;
  const bf16* gA1 = gA0 + (size_t)16 * Kd;
  const bf16* gB0 = Bt + (size_t)(n0 + ch * 16 + rA) * Kd + cE;
  const bf16* gB1 = gB0 + (size_t)16 * Kd;
  bf16* lA0 = As + ch * 512;
  bf16* lA1 = As + ch * 512 + 512;
  bf16* lB0 = Bs + ch * 512;
  bf16* lB1 = Bs + ch * 512 + 512;

  for (int k0 = kBeg; k0 < kEnd; k0 += BK) {
    __syncthreads();
    gl2lds16(gA0 + k0, lA0);
    gl2lds16(gA1 + k0, lA1);
    gl2lds16(gB0 + k0, lB0);
    gl2lds16(gB1 + k0, lB1);
    __syncthreads();
    bf16x8 af[4], bfr[4];
#pragma unroll
    for (int mi = 0; mi < 4; mi++) af[mi] = *(const bf16x8*)&As[(wm * 64 + mi * 16 + l16) * BK + quad * 8];
#pragma unroll
    for (int ni = 0; ni < 4; ni++) bfr[ni] = *(const bf16x8*)&Bs[(wn * 64 + ni * 16 + l16) * BK + quad * 8];
#pragma unroll
    for (int mi = 0; mi < 4; mi++)
#pragma unroll
      for (int ni = 0; ni < 4; ni++) acc[mi][ni] = mfma16(af[mi], bfr[ni], acc[mi][ni]);
  }

  if constexpr (MODE == 2) {
    float* outP = args.outP[z];
#pragma unroll
    for (int mi = 0; mi < 4; mi++) {
#pragma unroll
      for (int r = 0; r < 4; r++) {
        int row = m0 + wm * 64 + mi * 16 + quad * 4 + r;  // C/D: row=quad*4+reg (m89-verified)
#pragma unroll
        for (int ni = 0; ni < 4; ni++) {
          int col = n0 + wn * 64 + ni * 16 + l16;
          outP[(size_t)row * N + col] = acc[mi][ni][r];
        }
      }
    }
  } else {
    const float* bias = args.bias[z];
    bf16* outB = args.outB[z];
    float bv[4];
#pragma unroll
    for (int ni = 0; ni < 4; ni++) bv[ni] = bias[n0 + wn * 64 + ni * 16 + l16];
#pragma unroll
    for (int mi = 0; mi < 4; mi++) {
#pragma unroll
      for (int r = 0; r < 4; r++) {
        int row = m0 + wm * 64 + mi * 16 + quad * 4 + r;
#pragma unroll
        for (int ni = 0; ni < 4; ni++) {
          int col = n0 + wn * 64 + ni * 16 + l16;
          float v = acc[mi][ni][r] + bv[ni];
          if constexpr (MODE == 1) v = 0.5f * v * (1.0f + erff(v * 0.70710678118654752f));
          outB[(size_t)row * N + col] = (bf16)v;
        }
      }
    }
  }
}

// ---------------- attention: flash-style, batched-128 softmax ----------------
// grid (bh=96, qt=8): bid%8 = bh%8 -> all q-tiles of one head share an XCD L2.
#define CHK 128
__global__ __launch_bounds__(256) void attn_k(const bf16* __restrict__ Qg, const bf16* __restrict__ Kg,
                                              const bf16* __restrict__ Vg, const int* __restrict__ mask,
                                              bf16* __restrict__ ctx) {
  __shared__ bf16 Ks[CHK][72];              // K chunk [key][dh]        18432 B
  __shared__ unsigned int Vts[DHEAD][68];   // V^T, keys packed 2/u32   17408 B
  __shared__ float maskadd[CHK];            //                            512 B
  __shared__ bf16 Ps[4][16][136];           // per-wave P (C->A layout) 17408 B
  int bh = blockIdx.x;
  int b = bh / NHEAD, h = bh % NHEAD;
  int q0 = blockIdx.y * 64;
  int t = threadIdx.x;
  int wid = t >> 6, lane = t & 63, quad = lane >> 4, l16 = lane & 15;
  size_t base = (size_t)b * SEQ * H_DIM + (size_t)h * DHEAD;

  int qrow = q0 + wid * 16 + l16;
  bf16x8 qf0 = *(const bf16x8*)(Qg + base + (size_t)qrow * H_DIM + quad * 8);
  bf16x8 qf1 = *(const bf16x8*)(Qg + base + (size_t)qrow * H_DIM + 32 + quad * 8);

  f32x4 zero4 = {0.0f, 0.0f, 0.0f, 0.0f};
  f32x4 o[4];
  float m_i[4], l_i[4];
#pragma unroll
  for (int r = 0; r < 4; r++) { o[r] = zero4; m_i[r] = -1e30f; l_i[r] = 0.0f; }

  for (int c0 = 0; c0 < SEQ; c0 += CHK) {
    __syncthreads();
    {  // stage K chunk: 128 keys x 64 dh (row-wise b128, conflict-min)
      int row = t >> 1, half = (t & 1) * 32;
      const bf16* g = Kg + base + (size_t)(c0 + row) * H_DIM + half;
      *(bf16x8*)&Ks[row][half]      = *(const bf16x8*)g;
      *(bf16x8*)&Ks[row][half + 8]  = *(const bf16x8*)(g + 8);
      *(bf16x8*)&Ks[row][half + 16] = *(const bf16x8*)(g + 16);
      *(bf16x8*)&Ks[row][half + 24] = *(const bf16x8*)(g + 24);
    }
#pragma unroll
    for (int p = 0; p < 2; ++p) {  // stage V^T: 2 keys packed per u32 -> conflict-free writes
      int kp = t & 63;             // key pair 0..63
      int dg = ((t >> 6) + p * 4) * 8;
      const bf16* vp = Vg + base + (size_t)(c0 + 2 * kp) * H_DIM + dg;
      bf16x8 v0 = *(const bf16x8*)vp;
      bf16x8 v1 = *(const bf16x8*)(vp + H_DIM);
      const unsigned short* u0 = (const unsigned short*)&v0;
      const unsigned short* u1 = (const unsigned short*)&v1;
#pragma unroll
      for (int j = 0; j < 8; j++)
        Vts[dg + j][kp] = (unsigned int)u0[j] | ((unsigned int)u1[j] << 16);
    }
    if (t < CHK) maskadd[t] = (1.0f - (float)mask[b * SEQ + c0 + t]) * -10000.0f;
    __syncthreads();

    // QK^T: 16 independent MFMAs -> sc[8] covers 128 keys
    f32x4 sc[8];
#pragma unroll
    for (int k8 = 0; k8 < 8; k8++) {
      const bf16* krow = &Ks[k8 * 16 + l16][0];
      bf16x8 ka = *(const bf16x8*)(krow + quad * 8);
      bf16x8 kb = *(const bf16x8*)(krow + 32 + quad * 8);
      f32x4 s = mfma16(qf0, ka, zero4);
      sc[k8] = mfma16(qf1, kb, s);
    }
    float madd[8];
#pragma unroll
    for (int k8 = 0; k8 < 8; k8++) madd[k8] = maskadd[k8 * 16 + l16];

    // batched softmax over the 128-key chunk
#pragma unroll
    for (int r = 0; r < 4; r++) {
      float v[8], mx = -1e30f;
#pragma unroll
      for (int k8 = 0; k8 < 8; k8++) { v[k8] = sc[k8][r] * 0.125f + madd[k8]; mx = fmaxf(mx, v[k8]); }
#pragma unroll
      for (int off = 1; off < 16; off <<= 1) mx = fmaxf(mx, __shfl_xor(mx, off));
      float mnew = fmaxf(m_i[r], mx);
      float alpha = __expf(m_i[r] - mnew);
      m_i[r] = mnew;
      float ps = 0.0f;
#pragma unroll
      for (int k8 = 0; k8 < 8; k8++) { v[k8] = __expf(v[k8] - mnew); ps += v[k8]; }
#pragma unroll
      for (int off = 1; off < 16; off <<= 1) ps += __shfl_xor(ps, off);
      l_i[r] = l_i[r] * alpha + ps;
#pragma unroll
      for (int ni = 0; ni < 4; ni++) o[ni][r] *= alpha;
#pragma unroll
      for (int k8 = 0; k8 < 8; k8++) Ps[wid][quad * 4 + r][k8 * 16 + l16] = (bf16)v[k8];
    }

    // PV: P (A-layout from LDS) x V^T
#pragma unroll
    for (int kt = 0; kt < CHK; kt += 32) {
      bf16x8 pa = *(const bf16x8*)&Ps[wid][l16][kt + quad * 8];
#pragma unroll
      for (int ni = 0; ni < 4; ni++) {
        const bf16* vrow = (const bf16*)&Vts[ni * 16 + l16][0] + kt + quad * 8;
        o[ni] = mfma16(pa, *(const bf16x8*)vrow, o[ni]);
      }
    }
  }
#pragma unroll
  for (int r = 0; r < 4; r++) {
    int row = q0 + wid * 16 + quad * 4 + r;
    float inv = 1.0f / l_i[r];
#pragma unroll
    for (int ni = 0; ni < 4; ni++)
      ctx[base + (size_t)row * H_DIM + ni * 16 + l16] = (bf16)(o[ni][r] * inv);
  }
}

// --------- fused reduce(2 partials) + residual + bias + LayerNorm over H=768 ----------
__global__ __launch_bounds__(256) void redln_k(const float* __restrict__ p0, const float* __restrict__ p1,
                                               const float* __restrict__ resF, const bf16* __restrict__ resB,
                                               const float* __restrict__ bias,
                                               const float* __restrict__ g, const float* __restrict__ bta,
                                               bf16* __restrict__ outB, float* __restrict__ outF) {
  int row = blockIdx.x, t = threadIdx.x;
  size_t base = (size_t)row * H_DIM;
  float v[3], s = 0.0f, sq = 0.0f;
#pragma unroll
  for (int i = 0; i < 3; i++) {
    int c = t + i * 256;
    float r = resF ? resF[base + c] : (float)resB[base + c];
    float x = p0[base + c] + p1[base + c] + bias[c] + r;
    v[i] = x; s += x; sq += x * x;
  }
#pragma unroll
  for (int off = 32; off >= 1; off >>= 1) { s += __shfl_down(s, off); sq += __shfl_down(sq, off); }
  __shared__ float ssum[4], ssq[4], smu, srs;
  int lane = t & 63, w = t >> 6;
  if (lane == 0) { ssum[w] = s; ssq[w] = sq; }
  __syncthreads();
  if (t == 0) {
    float S = ssum[0] + ssum[1] + ssum[2] + ssum[3];
    float Q = ssq[0] + ssq[1] + ssq[2] + ssq[3];
    float mu = S * (1.0f / H_DIM);
    float var = Q * (1.0f / H_DIM) - mu * mu;
    smu = mu;
    srs = rsqrtf(var + 1e-3f);
  }
  __syncthreads();
  float mu = smu, rs = srs;
#pragma unroll
  for (int i = 0; i < 3; i++) {
    int c = t + i * 256;
    float y = (v[i] - mu) * rs * g[c] + bta[c];
    if (outB) outB[base + c] = (bf16)y;
    if (outF) outF[base + c] = y;
  }
}

extern "C" void kernel_launch(void* const* d_in, const int* in_sizes, int n_in,
                              void* d_out, int out_size, void* d_ws, size_t ws_size,
                              hipStream_t stream) {
  const float* x    = (const float*)d_in[0];
  const int*   mask = (const int*)d_in[1];
  const float* Wq = (const float*)d_in[2];  const float* bq = (const float*)d_in[3];
  const float* Wk = (const float*)d_in[4];  const float* bk = (const float*)d_in[5];
  const float* Wv = (const float*)d_in[6];  const float* bv = (const float*)d_in[7];
  const float* Wo = (const float*)d_in[8];  const float* bo = (const float*)d_in[9];
  const float* ln1g = (const float*)d_in[10]; const float* ln1b = (const float*)d_in[11];
  const float* W1 = (const float*)d_in[12]; const float* b1 = (const float*)d_in[13];
  const float* W2 = (const float*)d_in[14]; const float* b2 = (const float*)d_in[15];
  const float* ln2g = (const float*)d_in[16]; const float* ln2b = (const float*)d_in[17];
  float* out = (float*)d_out;
  (void)ws_size; (void)in_sizes; (void)n_in; (void)out_size;

  // ---- workspace: exact lifetime aliasing, peak ~61.3 MB ----
  char* w = (char*)d_ws;
  const size_t SZ_TH  = 6291456;    // bf16 TOK x H
  const size_t SZ_THF = 12582912;   // fp32 TOK x H
  const size_t SZ_W   = 1179648;    // bf16 H x H
  bf16* xB   = (bf16*)(w);                        // dead after QKV
  bf16* QB   = (bf16*)(w + SZ_TH);                // dead after attn
  bf16* KB   = (bf16*)(w + 2 * SZ_TH);
  bf16* VB   = (bf16*)(w + 3 * SZ_TH);
  float* P1s0 = (float*)(w);                      // over xB+QB (dead)
  float* P1s1 = (float*)(w + SZ_THF);             // over KB+VB (dead)
  bf16* FFA  = (bf16*)(w);                        // over P1 (dead after redLN1)
  bf16* CTX  = (bf16*)(w + 4 * SZ_TH);            // dead after Wo-gemm
  bf16* H1   = CTX;                               // redLN1 out; alive till redLN2
  bf16* WqT  = (bf16*)(w + 5 * SZ_TH);            // dead after QKV
  bf16* WkT  = (bf16*)(w + 5 * SZ_TH + SZ_W);
  bf16* WvT  = (bf16*)(w + 5 * SZ_TH + 2 * SZ_W);
  bf16* WoT  = (bf16*)(w + 5 * SZ_TH + 3 * SZ_W); // dead after Wo-gemm
  bf16* W1T  = (bf16*)(w + 5 * SZ_TH + 4 * SZ_W); // dead after FF1
  float* P2s0 = (float*)(w + 5 * SZ_TH);          // over WqT..W1T (dead by FF2)
  float* P2s1 = (float*)(w + 5 * SZ_TH + SZ_THF);
  bf16* W2T  = (bf16*)(w + 5 * SZ_TH + 2 * SZ_THF); // alive till FF2-gemm

  dim3 tb(256);

  // conversions: x straight; weights transpose+convert to [N][K] (4 HxH fused in one launch)
  cvt_k<<<(TOK * H_DIM) / 2048, tb, 0, stream>>>(x, xB, TOK * H_DIM);
  CvtTArgs ct = {};
  ct.in[0] = Wq; ct.in[1] = Wk; ct.in[2] = Wv; ct.in[3] = Wo;
  ct.out[0] = WqT; ct.out[1] = WkT; ct.out[2] = WvT; ct.out[3] = WoT;
  cvtT_k<<<dim3(24, 24, 4), tb, 0, stream>>>(ct, H_DIM, H_DIM);
  CvtTArgs c1 = {}; c1.in[0] = W1; c1.out[0] = W1T;
  cvtT_k<<<dim3(96, 24, 1), tb, 0, stream>>>(c1, H_DIM, FF_DIM);
  CvtTArgs c2 = {}; c2.in[0] = W2; c2.out[0] = W2T;
  cvtT_k<<<dim3(24, 96, 1), tb, 0, stream>>>(c2, FF_DIM, H_DIM);

  // QKV: MODE 0, 1-D grid 6*32*3 = 576, XCD-swizzled (ry=4)
  GemmArgs ga = {};
  ga.A = xB; ga.N = H_DIM; ga.K = H_DIM; ga.nx = 6; ga.ry = 4; ga.kSlices = 1;
  ga.W[0] = WqT; ga.W[1] = WkT; ga.W[2] = WvT;
  ga.bias[0] = bq; ga.bias[1] = bk; ga.bias[2] = bv;
  ga.outB[0] = QB; ga.outB[1] = KB; ga.outB[2] = VB;
  gemm_x<0><<<576, tb, 0, stream>>>(ga);

  // attention: grid (bh, qt) so one head's q-tiles share an XCD
  attn_k<<<dim3(8 * NHEAD, SEQ / 64), tb, 0, stream>>>(QB, KB, VB, mask, CTX);

  // Wo-proj: MODE 2 split-K=2, grid 384
  GemmArgs go = {};
  go.A = CTX; go.N = H_DIM; go.K = H_DIM; go.nx = 6; go.ry = 4; go.kSlices = 2;
  go.W[0] = WoT; go.outP[0] = P1s0; go.outP[1] = P1s1;
  gemm_x<2><<<384, tb, 0, stream>>>(go);

  // reduce + residual(x) + bias(bo) + LN1 -> H1 (bf16)
  redln_k<<<TOK, tb, 0, stream>>>(P1s0, P1s1, x, nullptr, bo, ln1g, ln1b, H1, nullptr);

  // FF1 + GELU: MODE 1, grid 768
  GemmArgs g1 = {};
  g1.A = H1; g1.N = FF_DIM; g1.K = H_DIM; g1.nx = 24; g1.ry = 4; g1.kSlices = 1;
  g1.W[0] = W1T; g1.bias[0] = b1; g1.outB[0] = FFA;
  gemm_x<1><<<768, tb, 0, stream>>>(g1);

  // FF2: MODE 2 split-K=2, grid 384
  GemmArgs g2 = {};
  g2.A = FFA; g2.N = H_DIM; g2.K = FF_DIM; g2.nx = 6; g2.ry = 4; g2.kSlices = 2;
  g2.W[0] = W2T; g2.outP[0] = P2s0; g2.outP[1] = P2s1;
  gemm_x<2><<<384, tb, 0, stream>>>(g2);

  // reduce + residual(H1 bf16) + bias(b2) + LN2 -> out (fp32)
  redln_k<<<TOK, tb, 0, stream>>>(P2s0, P2s1, nullptr, H1, b2, ln2g, ln2b, nullptr, out);
}

// Round 9
// 277.489 us; speedup vs baseline: 1.3277x; 1.0308x over previous
//
#include <hip/hip_runtime.h>
#include <hip/hip_bf16.h>

// BERT layer: B=8,S=512,H=768,NH=12,DH=64,FF=3072. Inputs fp32, mask int32, out fp32.
// bf16 MFMA + fp32 accum. GEMM: BM=128 BN=64, double-staged BK=64 (2x32 halves),
// global_load_lds w16, XCD-swizzled 1-D grids. Wo/FF2: split-K=2 + fused reduce+LN.
#define H_DIM 768
#define FF_DIM 3072
#define NHEAD 12
#define DHEAD 64
#define SEQ 512
#define TOK 4096

typedef __bf16 bf16;
using bf16x8 = __attribute__((ext_vector_type(8))) __bf16;
using f32x4  = __attribute__((ext_vector_type(4))) float;

static __device__ __forceinline__ f32x4 mfma16(bf16x8 a, bf16x8 b, f32x4 c) {
  return __builtin_amdgcn_mfma_f32_16x16x32_bf16(a, b, c, 0, 0, 0);
}

static __device__ __forceinline__ void gl2lds16(const bf16* g, bf16* l) {
  __builtin_amdgcn_global_load_lds((const __attribute__((address_space(1))) void*)g,
                                   (__attribute__((address_space(3))) void*)l, 16, 0, 0);
}

// ---------------- fp32 -> bf16 conversion (n divisible by 2048) ----------------
__global__ __launch_bounds__(256) void cvt_k(const float* __restrict__ in, bf16* __restrict__ out, int n) {
  int i = (blockIdx.x * 256 + threadIdx.x) * 8;
  if (i >= n) return;
  float4 a = *(const float4*)(in + i);
  float4 b = *(const float4*)(in + i + 4);
  bf16x8 o;
  o[0] = (bf16)a.x; o[1] = (bf16)a.y; o[2] = (bf16)a.z; o[3] = (bf16)a.w;
  o[4] = (bf16)b.x; o[5] = (bf16)b.y; o[6] = (bf16)b.z; o[7] = (bf16)b.w;
  *(bf16x8*)(out + i) = o;
}

// ------- fused transpose+convert: fp32 in[R][C] -> bf16 out[C][R]; z selects tensor -------
struct CvtTArgs { const float* in[4]; bf16* out[4]; };
__global__ __launch_bounds__(256) void cvtT_k(CvtTArgs args, int R, int C) {
  __shared__ bf16 tile[32][33];
  const float* in = args.in[blockIdx.z];
  bf16* out = args.out[blockIdx.z];
  int c0 = blockIdx.x * 32, r0 = blockIdx.y * 32;
  int tx = threadIdx.x & 31, ty = threadIdx.x >> 5;  // 32 x 8
  for (int i = 0; i < 32; i += 8) tile[ty + i][tx] = (bf16)in[(size_t)(r0 + ty + i) * C + c0 + tx];
  __syncthreads();
  for (int i = 0; i < 32; i += 8) out[(size_t)(c0 + ty + i) * R + r0 + tx] = tile[tx][ty + i];
}

// -------- GEMM: BM=128 x BN=64 tile, BK=64 (two 32-halves), XCD-swizzled 1-D grid --------
// MODE 0: out = bf16(acc + bias)        MODE 1: out = bf16(gelu(acc + bias))
// MODE 2: outP[z][row*N+col] = acc      (split-K partial, plain fp32 stores)
struct GemmArgs {
  const bf16* A;
  const bf16* W[3];      // transposed weights [N][K]
  const float* bias[3];
  bf16* outB[3];
  float* outP[2];
  int N, K, nx, ry, kSlices;  // ry = (M/128)/8 rows per XCD
};

template <int MODE>
__global__ __launch_bounds__(256) void gemm_x(GemmArgs args) {
  __shared__ bf16 As[2][128 * 32];   // two k-halves, [row][32] unpadded
  __shared__ bf16 Bs[2][64 * 32];
  int bid = blockIdx.x;
  int xcd = bid & 7, tt = bid >> 3;
  int ry = args.ry;
  int by = xcd * ry + (tt % ry);
  int rest = tt / ry;
  int bx = rest % args.nx;
  int z = rest / args.nx;

  const bf16* A = args.A;
  const bf16* Bt;
  int Kd = args.K, N = args.N;
  int kBeg, kEnd;
  if constexpr (MODE == 2) {
    Bt = args.W[0];
    int ks = Kd / args.kSlices;
    kBeg = z * ks; kEnd = kBeg + ks;
  } else {
    Bt = args.W[z];
    kBeg = 0; kEnd = Kd;
  }
  int m0 = by * 128, n0 = bx * 64;
  int t = threadIdx.x;
  int wid = t >> 6, lane = t & 63, quad = lane >> 4, l16 = lane & 15;
  int wm = wid >> 1, wn = wid & 1;

  f32x4 zero4 = {0.0f, 0.0f, 0.0f, 0.0f};
  f32x4 acc[4][2];
#pragma unroll
  for (int mi = 0; mi < 4; mi++)
#pragma unroll
    for (int ni = 0; ni < 2; ni++) acc[mi][ni] = zero4;

  // staging: chunk = 16 rows x 32 cols = 1 KB (one wave-load).
  // A: 8 chunks/half, wave owns {2wid, 2wid+1}. B: 4 chunks/half, wave owns {wid}.
  int rA = lane >> 2;            // row within chunk
  int cE = (lane & 3) * 8;       // col elem
  const bf16* gA0 = A  + (size_t)(m0 + wid * 32 + rA) * Kd + cE;
  const bf16* gA1 = gA0 + (size_t)16 * Kd;
  const bf16* gB0 = Bt + (size_t)(n0 + wid * 16 + rA) * Kd + cE;
  bf16* lA0 = &As[0][wid * 1024];
  bf16* lA1 = &As[0][wid * 1024 + 512];
  bf16* lB0 = &Bs[0][wid * 512];
  bf16* lA2 = &As[1][wid * 1024];
  bf16* lA3 = &As[1][wid * 1024 + 512];
  bf16* lB1 = &Bs[1][wid * 512];

  for (int k0 = kBeg; k0 < kEnd; k0 += 64) {
    __syncthreads();
    gl2lds16(gA0 + k0, lA0);
    gl2lds16(gA1 + k0, lA1);
    gl2lds16(gB0 + k0, lB0);
    gl2lds16(gA0 + k0 + 32, lA2);
    gl2lds16(gA1 + k0 + 32, lA3);
    gl2lds16(gB0 + k0 + 32, lB1);
    __syncthreads();
#pragma unroll
    for (int h = 0; h < 2; h++) {
      bf16x8 af[4], bfr[2];
#pragma unroll
      for (int mi = 0; mi < 4; mi++) af[mi] = *(const bf16x8*)&As[h][(wm * 64 + mi * 16 + l16) * 32 + quad * 8];
#pragma unroll
      for (int ni = 0; ni < 2; ni++) bfr[ni] = *(const bf16x8*)&Bs[h][(wn * 32 + ni * 16 + l16) * 32 + quad * 8];
#pragma unroll
      for (int mi = 0; mi < 4; mi++)
#pragma unroll
        for (int ni = 0; ni < 2; ni++) acc[mi][ni] = mfma16(af[mi], bfr[ni], acc[mi][ni]);
    }
  }

  if constexpr (MODE == 2) {
    float* outP = args.outP[z];
#pragma unroll
    for (int mi = 0; mi < 4; mi++) {
#pragma unroll
      for (int r = 0; r < 4; r++) {
        int row = m0 + wm * 64 + mi * 16 + quad * 4 + r;  // C/D: row=quad*4+reg (m89-verified)
#pragma unroll
        for (int ni = 0; ni < 2; ni++) {
          int col = n0 + wn * 32 + ni * 16 + l16;
          outP[(size_t)row * N + col] = acc[mi][ni][r];
        }
      }
    }
  } else {
    const float* bias = args.bias[z];
    bf16* outB = args.outB[z];
    float bv[2];
#pragma unroll
    for (int ni = 0; ni < 2; ni++) bv[ni] = bias[n0 + wn * 32 + ni * 16 + l16];
#pragma unroll
    for (int mi = 0; mi < 4; mi++) {
#pragma unroll
      for (int r = 0; r < 4; r++) {
        int row = m0 + wm * 64 + mi * 16 + quad * 4 + r;
#pragma unroll
        for (int ni = 0; ni < 2; ni++) {
          int col = n0 + wn * 32 + ni * 16 + l16;
          float v = acc[mi][ni][r] + bv[ni];
          if constexpr (MODE == 1) v = 0.5f * v * (1.0f + erff(v * 0.70710678118654752f));
          outB[(size_t)row * N + col] = (bf16)v;
        }
      }
    }
  }
}

// ---------------- attention: flash-style, batched-128 softmax ----------------
// grid (bh=96, qt=8): bid%8 = bh%8 -> all q-tiles of one head share an XCD L2.
#define CHK 128
__global__ __launch_bounds__(256) void attn_k(const bf16* __restrict__ Qg, const bf16* __restrict__ Kg,
                                              const bf16* __restrict__ Vg, const int* __restrict__ mask,
                                              bf16* __restrict__ ctx) {
  __shared__ bf16 Ks[CHK][72];
  __shared__ unsigned int Vts[DHEAD][68];   // V^T, keys packed 2/u32
  __shared__ float maskadd[CHK];
  __shared__ bf16 Ps[4][16][136];
  int bh = blockIdx.x;
  int b = bh / NHEAD, h = bh % NHEAD;
  int q0 = blockIdx.y * 64;
  int t = threadIdx.x;
  int wid = t >> 6, lane = t & 63, quad = lane >> 4, l16 = lane & 15;
  size_t base = (size_t)b * SEQ * H_DIM + (size_t)h * DHEAD;

  int qrow = q0 + wid * 16 + l16;
  bf16x8 qf0 = *(const bf16x8*)(Qg + base + (size_t)qrow * H_DIM + quad * 8);
  bf16x8 qf1 = *(const bf16x8*)(Qg + base + (size_t)qrow * H_DIM + 32 + quad * 8);

  f32x4 zero4 = {0.0f, 0.0f, 0.0f, 0.0f};
  f32x4 o[4];
  float m_i[4], l_i[4];
#pragma unroll
  for (int r = 0; r < 4; r++) { o[r] = zero4; m_i[r] = -1e30f; l_i[r] = 0.0f; }

  for (int c0 = 0; c0 < SEQ; c0 += CHK) {
    __syncthreads();
    {
      int row = t >> 1, half = (t & 1) * 32;
      const bf16* g = Kg + base + (size_t)(c0 + row) * H_DIM + half;
      *(bf16x8*)&Ks[row][half]      = *(const bf16x8*)g;
      *(bf16x8*)&Ks[row][half + 8]  = *(const bf16x8*)(g + 8);
      *(bf16x8*)&Ks[row][half + 16] = *(const bf16x8*)(g + 16);
      *(bf16x8*)&Ks[row][half + 24] = *(const bf16x8*)(g + 24);
    }
#pragma unroll
    for (int p = 0; p < 2; ++p) {
      int kp = t & 63;
      int dg = ((t >> 6) + p * 4) * 8;
      const bf16* vp = Vg + base + (size_t)(c0 + 2 * kp) * H_DIM + dg;
      bf16x8 v0 = *(const bf16x8*)vp;
      bf16x8 v1 = *(const bf16x8*)(vp + H_DIM);
      const unsigned short* u0 = (const unsigned short*)&v0;
      const unsigned short* u1 = (const unsigned short*)&v1;
#pragma unroll
      for (int j = 0; j < 8; j++)
        Vts[dg + j][kp] = (unsigned int)u0[j] | ((unsigned int)u1[j] << 16);
    }
    if (t < CHK) maskadd[t] = (1.0f - (float)mask[b * SEQ + c0 + t]) * -10000.0f;
    __syncthreads();

    f32x4 sc[8];
#pragma unroll
    for (int k8 = 0; k8 < 8; k8++) {
      const bf16* krow = &Ks[k8 * 16 + l16][0];
      bf16x8 ka = *(const bf16x8*)(krow + quad * 8);
      bf16x8 kb = *(const bf16x8*)(krow + 32 + quad * 8);
      f32x4 s = mfma16(qf0, ka, zero4);
      sc[k8] = mfma16(qf1, kb, s);
    }
    float madd[8];
#pragma unroll
    for (int k8 = 0; k8 < 8; k8++) madd[k8] = maskadd[k8 * 16 + l16];

#pragma unroll
    for (int r = 0; r < 4; r++) {
      float v[8], mx = -1e30f;
#pragma unroll
      for (int k8 = 0; k8 < 8; k8++) { v[k8] = sc[k8][r] * 0.125f + madd[k8]; mx = fmaxf(mx, v[k8]); }
#pragma unroll
      for (int off = 1; off < 16; off <<= 1) mx = fmaxf(mx, __shfl_xor(mx, off));
      float mnew = fmaxf(m_i[r], mx);
      float alpha = __expf(m_i[r] - mnew);
      m_i[r] = mnew;
      float ps = 0.0f;
#pragma unroll
      for (int k8 = 0; k8 < 8; k8++) { v[k8] = __expf(v[k8] - mnew); ps += v[k8]; }
#pragma unroll
      for (int off = 1; off < 16; off <<= 1) ps += __shfl_xor(ps, off);
      l_i[r] = l_i[r] * alpha + ps;
#pragma unroll
      for (int ni = 0; ni < 4; ni++) o[ni][r] *= alpha;
#pragma unroll
      for (int k8 = 0; k8 < 8; k8++) Ps[wid][quad * 4 + r][k8 * 16 + l16] = (bf16)v[k8];
    }

#pragma unroll
    for (int kt = 0; kt < CHK; kt += 32) {
      bf16x8 pa = *(const bf16x8*)&Ps[wid][l16][kt + quad * 8];
#pragma unroll
      for (int ni = 0; ni < 4; ni++) {
        const bf16* vrow = (const bf16*)&Vts[ni * 16 + l16][0] + kt + quad * 8;
        o[ni] = mfma16(pa, *(const bf16x8*)vrow, o[ni]);
      }
    }
  }
#pragma unroll
  for (int r = 0; r < 4; r++) {
    int row = q0 + wid * 16 + quad * 4 + r;
    float inv = 1.0f / l_i[r];
#pragma unroll
    for (int ni = 0; ni < 4; ni++)
      ctx[base + (size_t)row * H_DIM + ni * 16 + l16] = (bf16)(o[ni][r] * inv);
  }
}

// --------- fused reduce(2 partials) + residual + bias + LayerNorm over H=768 ----------
__global__ __launch_bounds__(256) void redln_k(const float* __restrict__ p0, const float* __restrict__ p1,
                                               const float* __restrict__ resF, const bf16* __restrict__ resB,
                                               const float* __restrict__ bias,
                                               const float* __restrict__ g, const float* __restrict__ bta,
                                               bf16* __restrict__ outB, float* __restrict__ outF) {
  int row = blockIdx.x, t = threadIdx.x;
  size_t base = (size_t)row * H_DIM;
  float v[3], s = 0.0f, sq = 0.0f;
#pragma unroll
  for (int i = 0; i < 3; i++) {
    int c = t + i * 256;
    float r = resF ? resF[base + c] : (float)resB[base + c];
    float x = p0[base + c] + p1[base + c] + bias[c] + r;
    v[i] = x; s += x; sq += x * x;
  }
#pragma unroll
  for (int off = 32; off >= 1; off >>= 1) { s += __shfl_down(s, off); sq += __shfl_down(sq, off); }
  __shared__ float ssum[4], ssq[4], smu, srs;
  int lane = t & 63, w = t >> 6;
  if (lane == 0) { ssum[w] = s; ssq[w] = sq; }
  __syncthreads();
  if (t == 0) {
    float S = ssum[0] + ssum[1] + ssum[2] + ssum[3];
    float Q = ssq[0] + ssq[1] + ssq[2] + ssq[3];
    float mu = S * (1.0f / H_DIM);
    float var = Q * (1.0f / H_DIM) - mu * mu;
    smu = mu;
    srs = rsqrtf(var + 1e-3f);
  }
  __syncthreads();
  float mu = smu, rs = srs;
#pragma unroll
  for (int i = 0; i < 3; i++) {
    int c = t + i * 256;
    float y = (v[i] - mu) * rs * g[c] + bta[c];
    if (outB) outB[base + c] = (bf16)y;
    if (outF) outF[base + c] = y;
  }
}

extern "C" void kernel_launch(void* const* d_in, const int* in_sizes, int n_in,
                              void* d_out, int out_size, void* d_ws, size_t ws_size,
                              hipStream_t stream) {
  const float* x    = (const float*)d_in[0];
  const int*   mask = (const int*)d_in[1];
  const float* Wq = (const float*)d_in[2];  const float* bq = (const float*)d_in[3];
  const float* Wk = (const float*)d_in[4];  const float* bk = (const float*)d_in[5];
  const float* Wv = (const float*)d_in[6];  const float* bv = (const float*)d_in[7];
  const float* Wo = (const float*)d_in[8];  const float* bo = (const float*)d_in[9];
  const float* ln1g = (const float*)d_in[10]; const float* ln1b = (const float*)d_in[11];
  const float* W1 = (const float*)d_in[12]; const float* b1 = (const float*)d_in[13];
  const float* W2 = (const float*)d_in[14]; const float* b2 = (const float*)d_in[15];
  const float* ln2g = (const float*)d_in[16]; const float* ln2b = (const float*)d_in[17];
  float* out = (float*)d_out;
  (void)ws_size; (void)in_sizes; (void)n_in; (void)out_size;

  // ---- workspace: exact lifetime aliasing, peak ~61.3 MB ----
  char* w = (char*)d_ws;
  const size_t SZ_TH  = 6291456;    // bf16 TOK x H
  const size_t SZ_THF = 12582912;   // fp32 TOK x H
  const size_t SZ_W   = 1179648;    // bf16 H x H
  bf16* xB   = (bf16*)(w);                        // dead after QKV
  bf16* QB   = (bf16*)(w + SZ_TH);                // dead after attn
  bf16* KB   = (bf16*)(w + 2 * SZ_TH);
  bf16* VB   = (bf16*)(w + 3 * SZ_TH);
  float* P1s0 = (float*)(w);                      // over xB+QB (dead)
  float* P1s1 = (float*)(w + SZ_THF);             // over KB+VB (dead)
  bf16* FFA  = (bf16*)(w);                        // over P1 (dead after redLN1)
  bf16* CTX  = (bf16*)(w + 4 * SZ_TH);            // dead after Wo-gemm
  bf16* H1   = CTX;                               // redLN1 out; alive till redLN2
  bf16* WqT  = (bf16*)(w + 5 * SZ_TH);            // dead after QKV
  bf16* WkT  = (bf16*)(w + 5 * SZ_TH + SZ_W);
  bf16* WvT  = (bf16*)(w + 5 * SZ_TH + 2 * SZ_W);
  bf16* WoT  = (bf16*)(w + 5 * SZ_TH + 3 * SZ_W); // dead after Wo-gemm
  bf16* W1T  = (bf16*)(w + 5 * SZ_TH + 4 * SZ_W); // dead after FF1
  float* P2s0 = (float*)(w + 5 * SZ_TH);          // over WqT..W1T (dead by FF2)
  float* P2s1 = (float*)(w + 5 * SZ_TH + SZ_THF);
  bf16* W2T  = (bf16*)(w + 5 * SZ_TH + 2 * SZ_THF); // alive till FF2-gemm

  dim3 tb(256);

  // conversions
  cvt_k<<<(TOK * H_DIM) / 2048, tb, 0, stream>>>(x, xB, TOK * H_DIM);
  CvtTArgs ct = {};
  ct.in[0] = Wq; ct.in[1] = Wk; ct.in[2] = Wv; ct.in[3] = Wo;
  ct.out[0] = WqT; ct.out[1] = WkT; ct.out[2] = WvT; ct.out[3] = WoT;
  cvtT_k<<<dim3(24, 24, 4), tb, 0, stream>>>(ct, H_DIM, H_DIM);
  CvtTArgs c1 = {}; c1.in[0] = W1; c1.out[0] = W1T;
  cvtT_k<<<dim3(96, 24, 1), tb, 0, stream>>>(c1, H_DIM, FF_DIM);
  CvtTArgs c2 = {}; c2.in[0] = W2; c2.out[0] = W2T;
  cvtT_k<<<dim3(24, 96, 1), tb, 0, stream>>>(c2, FF_DIM, H_DIM);

  // QKV: MODE 0, nx=12 (BN=64), grid 8*4*12*3 = 1152
  GemmArgs ga = {};
  ga.A = xB; ga.N = H_DIM; ga.K = H_DIM; ga.nx = 12; ga.ry = 4; ga.kSlices = 1;
  ga.W[0] = WqT; ga.W[1] = WkT; ga.W[2] = WvT;
  ga.bias[0] = bq; ga.bias[1] = bk; ga.bias[2] = bv;
  ga.outB[0] = QB; ga.outB[1] = KB; ga.outB[2] = VB;
  gemm_x<0><<<1152, tb, 0, stream>>>(ga);

  // attention
  attn_k<<<dim3(8 * NHEAD, SEQ / 64), tb, 0, stream>>>(QB, KB, VB, mask, CTX);

  // Wo-proj: MODE 2 split-K=2, grid 8*4*12*2 = 768
  GemmArgs go = {};
  go.A = CTX; go.N = H_DIM; go.K = H_DIM; go.nx = 12; go.ry = 4; go.kSlices = 2;
  go.W[0] = WoT; go.outP[0] = P1s0; go.outP[1] = P1s1;
  gemm_x<2><<<768, tb, 0, stream>>>(go);

  // reduce + residual(x) + bias(bo) + LN1 -> H1 (bf16)
  redln_k<<<TOK, tb, 0, stream>>>(P1s0, P1s1, x, nullptr, bo, ln1g, ln1b, H1, nullptr);

  // FF1 + GELU: MODE 1, nx=48, grid 8*4*48 = 1536
  GemmArgs g1 = {};
  g1.A = H1; g1.N = FF_DIM; g1.K = H_DIM; g1.nx = 48; g1.ry = 4; g1.kSlices = 1;
  g1.W[0] = W1T; g1.bias[0] = b1; g1.outB[0] = FFA;
  gemm_x<1><<<1536, tb, 0, stream>>>(g1);

  // FF2: MODE 2 split-K=2, grid 768
  GemmArgs g2 = {};
  g2.A = FFA; g2.N = H_DIM; g2.K = FF_DIM; g2.nx = 12; g2.ry = 4; g2.kSlices = 2;
  g2.W[0] = W2T; g2.outP[0] = P2s0; g2.outP[1] = P2s1;
  gemm_x<2><<<768, tb, 0, stream>>>(g2);

  // reduce + residual(H1 bf16) + bias(b2) + LN2 -> out (fp32)
  redln_k<<<TOK, tb, 0, stream>>>(P2s0, P2s1, nullptr, H1, b2, ln2g, ln2b, nullptr, out);
}

// Round 10
// 276.201 us; speedup vs baseline: 1.3339x; 1.0047x over previous
//
#include <hip/hip_runtime.h>
#include <hip/hip_bf16.h>

// BERT layer: B=8,S=512,H=768,NH=12,DH=64,FF=3072. Inputs fp32, mask int32, out fp32.
// bf16 MFMA + fp32 accum. GEMM: BM=128 BN=64, BK=64 (2x32), global_load_lds w16,
// XOR-swizzled LDS chunks (kills 8-way b128 read conflicts), XCD-swizzled grids.
// Wo/FF2: split-K=2 + fused reduce+residual+LayerNorm.
#define H_DIM 768
#define FF_DIM 3072
#define NHEAD 12
#define DHEAD 64
#define SEQ 512
#define TOK 4096

typedef __bf16 bf16;
using bf16x8 = __attribute__((ext_vector_type(8))) __bf16;
using f32x4  = __attribute__((ext_vector_type(4))) float;

static __device__ __forceinline__ f32x4 mfma16(bf16x8 a, bf16x8 b, f32x4 c) {
  return __builtin_amdgcn_mfma_f32_16x16x32_bf16(a, b, c, 0, 0, 0);
}

static __device__ __forceinline__ void gl2lds16(const bf16* g, bf16* l) {
  __builtin_amdgcn_global_load_lds((const __attribute__((address_space(1))) void*)g,
                                   (__attribute__((address_space(3))) void*)l, 16, 0, 0);
}

// ---------------- fp32 -> bf16 conversion (n divisible by 2048) ----------------
__global__ __launch_bounds__(256) void cvt_k(const float* __restrict__ in, bf16* __restrict__ out, int n) {
  int i = (blockIdx.x * 256 + threadIdx.x) * 8;
  if (i >= n) return;
  float4 a = *(const float4*)(in + i);
  float4 b = *(const float4*)(in + i + 4);
  bf16x8 o;
  o[0] = (bf16)a.x; o[1] = (bf16)a.y; o[2] = (bf16)a.z; o[3] = (bf16)a.w;
  o[4] = (bf16)b.x; o[5] = (bf16)b.y; o[6] = (bf16)b.z; o[7] = (bf16)b.w;
  *(bf16x8*)(out + i) = o;
}

// ------- fused transpose+convert: fp32 in[R][C] -> bf16 out[C][R]; z selects tensor -------
struct CvtTArgs { const float* in[4]; bf16* out[4]; };
__global__ __launch_bounds__(256) void cvtT_k(CvtTArgs args, int R, int C) {
  __shared__ bf16 tile[32][33];
  const float* in = args.in[blockIdx.z];
  bf16* out = args.out[blockIdx.z];
  int c0 = blockIdx.x * 32, r0 = blockIdx.y * 32;
  int tx = threadIdx.x & 31, ty = threadIdx.x >> 5;  // 32 x 8
  for (int i = 0; i < 32; i += 8) tile[ty + i][tx] = (bf16)in[(size_t)(r0 + ty + i) * C + c0 + tx];
  __syncthreads();
  for (int i = 0; i < 32; i += 8) out[(size_t)(c0 + ty + i) * R + r0 + tx] = tile[tx][ty + i];
}

// -------- GEMM: BM=128 x BN=64 tile, BK=64 (two 32-halves), XCD-swizzled 1-D grid --------
// LDS chunk swizzle: LDS[row][c] holds global chunk c ^ ((row>>1)&3)  (16B chunks, 4/row).
// MODE 0: out = bf16(acc + bias)        MODE 1: out = bf16(gelu(acc + bias))
// MODE 2: outP[z][row*N+col] = acc      (split-K partial, plain fp32 stores)
struct GemmArgs {
  const bf16* A;
  const bf16* W[3];      // transposed weights [N][K]
  const float* bias[3];
  bf16* outB[3];
  float* outP[2];
  int N, K, nx, ry, kSlices;  // ry = (M/128)/8 rows per XCD
};

template <int MODE>
__global__ __launch_bounds__(256) void gemm_x(GemmArgs args) {
  __shared__ bf16 As[2][128 * 32];   // two k-halves, [row][32] unpadded
  __shared__ bf16 Bs[2][64 * 32];
  int bid = blockIdx.x;
  int xcd = bid & 7, tt = bid >> 3;
  int ry = args.ry;
  int by = xcd * ry + (tt % ry);
  int rest = tt / ry;
  int bx = rest % args.nx;
  int z = rest / args.nx;

  const bf16* A = args.A;
  const bf16* Bt;
  int Kd = args.K, N = args.N;
  int kBeg, kEnd;
  if constexpr (MODE == 2) {
    Bt = args.W[0];
    int ks = Kd / args.kSlices;
    kBeg = z * ks; kEnd = kBeg + ks;
  } else {
    Bt = args.W[z];
    kBeg = 0; kEnd = Kd;
  }
  int m0 = by * 128, n0 = bx * 64;
  int t = threadIdx.x;
  int wid = t >> 6, lane = t & 63, quad = lane >> 4, l16 = lane & 15;
  int wm = wid >> 1, wn = wid & 1;

  f32x4 zero4 = {0.0f, 0.0f, 0.0f, 0.0f};
  f32x4 acc[4][2];
#pragma unroll
  for (int mi = 0; mi < 4; mi++)
#pragma unroll
    for (int ni = 0; ni < 2; ni++) acc[mi][ni] = zero4;

  // staging: chunk = 16 rows x 32 cols = 1 KB. Lane layout: rA=lane>>2 (row),
  // lane&3 = LDS 16B-chunk index; global chunk = (lane&3) ^ ((rA>>1)&3).
  int rA = lane >> 2;
  int cE = (((lane & 3) ^ ((rA >> 1) & 3))) * 8;
  const bf16* gA0 = A  + (size_t)(m0 + wid * 32 + rA) * Kd + cE;
  const bf16* gA1 = gA0 + (size_t)16 * Kd;
  const bf16* gB0 = Bt + (size_t)(n0 + wid * 16 + rA) * Kd + cE;
  bf16* lA0 = &As[0][wid * 1024];
  bf16* lA1 = &As[0][wid * 1024 + 512];
  bf16* lB0 = &Bs[0][wid * 512];
  bf16* lA2 = &As[1][wid * 1024];
  bf16* lA3 = &As[1][wid * 1024 + 512];
  bf16* lB1 = &Bs[1][wid * 512];

  int rsw = ((l16 >> 1) & 3);     // read-side row swizzle (row bits reduce to l16 bits)

  for (int k0 = kBeg; k0 < kEnd; k0 += 64) {
    __syncthreads();
    gl2lds16(gA0 + k0, lA0);
    gl2lds16(gA1 + k0, lA1);
    gl2lds16(gB0 + k0, lB0);
    gl2lds16(gA0 + k0 + 32, lA2);
    gl2lds16(gA1 + k0 + 32, lA3);
    gl2lds16(gB0 + k0 + 32, lB1);
    __syncthreads();
#pragma unroll
    for (int h = 0; h < 2; h++) {
      int cq = (quad ^ rsw) * 8;
      bf16x8 af[4], bfr[2];
#pragma unroll
      for (int mi = 0; mi < 4; mi++) af[mi] = *(const bf16x8*)&As[h][(wm * 64 + mi * 16 + l16) * 32 + cq];
#pragma unroll
      for (int ni = 0; ni < 2; ni++) bfr[ni] = *(const bf16x8*)&Bs[h][(wn * 32 + ni * 16 + l16) * 32 + cq];
#pragma unroll
      for (int mi = 0; mi < 4; mi++)
#pragma unroll
        for (int ni = 0; ni < 2; ni++) acc[mi][ni] = mfma16(af[mi], bfr[ni], acc[mi][ni]);
    }
  }

  if constexpr (MODE == 2) {
    float* outP = args.outP[z];
#pragma unroll
    for (int mi = 0; mi < 4; mi++) {
#pragma unroll
      for (int r = 0; r < 4; r++) {
        int row = m0 + wm * 64 + mi * 16 + quad * 4 + r;  // C/D: row=quad*4+reg (m89-verified)
#pragma unroll
        for (int ni = 0; ni < 2; ni++) {
          int col = n0 + wn * 32 + ni * 16 + l16;
          outP[(size_t)row * N + col] = acc[mi][ni][r];
        }
      }
    }
  } else {
    const float* bias = args.bias[z];
    bf16* outB = args.outB[z];
    float bv[2];
#pragma unroll
    for (int ni = 0; ni < 2; ni++) bv[ni] = bias[n0 + wn * 32 + ni * 16 + l16];
#pragma unroll
    for (int mi = 0; mi < 4; mi++) {
#pragma unroll
      for (int r = 0; r < 4; r++) {
        int row = m0 + wm * 64 + mi * 16 + quad * 4 + r;
#pragma unroll
        for (int ni = 0; ni < 2; ni++) {
          int col = n0 + wn * 32 + ni * 16 + l16;
          float v = acc[mi][ni][r] + bv[ni];
          if constexpr (MODE == 1) v = 0.5f * v * (1.0f + erff(v * 0.70710678118654752f));
          outB[(size_t)row * N + col] = (bf16)v;
        }
      }
    }
  }
}

// ---------------- attention: flash-style, batched-128 softmax ----------------
// grid (bh=96, qt=8): bid%8 = bh%8 -> all q-tiles of one head share an XCD L2.
#define CHK 128
__global__ __launch_bounds__(256) void attn_k(const bf16* __restrict__ Qg, const bf16* __restrict__ Kg,
                                              const bf16* __restrict__ Vg, const int* __restrict__ mask,
                                              bf16* __restrict__ ctx) {
  __shared__ bf16 Ks[CHK][72];
  __shared__ unsigned int Vts[DHEAD][68];   // V^T, keys packed 2/u32
  __shared__ float maskadd[CHK];
  __shared__ bf16 Ps[4][16][136];
  int bh = blockIdx.x;
  int b = bh / NHEAD, h = bh % NHEAD;
  int q0 = blockIdx.y * 64;
  int t = threadIdx.x;
  int wid = t >> 6, lane = t & 63, quad = lane >> 4, l16 = lane & 15;
  size_t base = (size_t)b * SEQ * H_DIM + (size_t)h * DHEAD;

  int qrow = q0 + wid * 16 + l16;
  bf16x8 qf0 = *(const bf16x8*)(Qg + base + (size_t)qrow * H_DIM + quad * 8);
  bf16x8 qf1 = *(const bf16x8*)(Qg + base + (size_t)qrow * H_DIM + 32 + quad * 8);

  f32x4 zero4 = {0.0f, 0.0f, 0.0f, 0.0f};
  f32x4 o[4];
  float m_i[4], l_i[4];
#pragma unroll
  for (int r = 0; r < 4; r++) { o[r] = zero4; m_i[r] = -1e30f; l_i[r] = 0.0f; }

  for (int c0 = 0; c0 < SEQ; c0 += CHK) {
    __syncthreads();
    {
      int row = t >> 1, half = (t & 1) * 32;
      const bf16* g = Kg + base + (size_t)(c0 + row) * H_DIM + half;
      *(bf16x8*)&Ks[row][half]      = *(const bf16x8*)g;
      *(bf16x8*)&Ks[row][half + 8]  = *(const bf16x8*)(g + 8);
      *(bf16x8*)&Ks[row][half + 16] = *(const bf16x8*)(g + 16);
      *(bf16x8*)&Ks[row][half + 24] = *(const bf16x8*)(g + 24);
    }
#pragma unroll
    for (int p = 0; p < 2; ++p) {
      int kp = t & 63;
      int dg = ((t >> 6) + p * 4) * 8;
      const bf16* vp = Vg + base + (size_t)(c0 + 2 * kp) * H_DIM + dg;
      bf16x8 v0 = *(const bf16x8*)vp;
      bf16x8 v1 = *(const bf16x8*)(vp + H_DIM);
      const unsigned short* u0 = (const unsigned short*)&v0;
      const unsigned short* u1 = (const unsigned short*)&v1;
#pragma unroll
      for (int j = 0; j < 8; j++)
        Vts[dg + j][kp] = (unsigned int)u0[j] | ((unsigned int)u1[j] << 16);
    }
    if (t < CHK) maskadd[t] = (1.0f - (float)mask[b * SEQ + c0 + t]) * -10000.0f;
    __syncthreads();

    f32x4 sc[8];
#pragma unroll
    for (int k8 = 0; k8 < 8; k8++) {
      const bf16* krow = &Ks[k8 * 16 + l16][0];
      bf16x8 ka = *(const bf16x8*)(krow + quad * 8);
      bf16x8 kb = *(const bf16x8*)(krow + 32 + quad * 8);
      f32x4 s = mfma16(qf0, ka, zero4);
      sc[k8] = mfma16(qf1, kb, s);
    }
    float madd[8];
#pragma unroll
    for (int k8 = 0; k8 < 8; k8++) madd[k8] = maskadd[k8 * 16 + l16];

#pragma unroll
    for (int r = 0; r < 4; r++) {
      float v[8], mx = -1e30f;
#pragma unroll
      for (int k8 = 0; k8 < 8; k8++) { v[k8] = sc[k8][r] * 0.125f + madd[k8]; mx = fmaxf(mx, v[k8]); }
#pragma unroll
      for (int off = 1; off < 16; off <<= 1) mx = fmaxf(mx, __shfl_xor(mx, off));
      float mnew = fmaxf(m_i[r], mx);
      float alpha = __expf(m_i[r] - mnew);
      m_i[r] = mnew;
      float ps = 0.0f;
#pragma unroll
      for (int k8 = 0; k8 < 8; k8++) { v[k8] = __expf(v[k8] - mnew); ps += v[k8]; }
#pragma unroll
      for (int off = 1; off < 16; off <<= 1) ps += __shfl_xor(ps, off);
      l_i[r] = l_i[r] * alpha + ps;
#pragma unroll
      for (int ni = 0; ni < 4; ni++) o[ni][r] *= alpha;
#pragma unroll
      for (int k8 = 0; k8 < 8; k8++) Ps[wid][quad * 4 + r][k8 * 16 + l16] = (bf16)v[k8];
    }

#pragma unroll
    for (int kt = 0; kt < CHK; kt += 32) {
      bf16x8 pa = *(const bf16x8*)&Ps[wid][l16][kt + quad * 8];
#pragma unroll
      for (int ni = 0; ni < 4; ni++) {
        const bf16* vrow = (const bf16*)&Vts[ni * 16 + l16][0] + kt + quad * 8;
        o[ni] = mfma16(pa, *(const bf16x8*)vrow, o[ni]);
      }
    }
  }
#pragma unroll
  for (int r = 0; r < 4; r++) {
    int row = q0 + wid * 16 + quad * 4 + r;
    float inv = 1.0f / l_i[r];
#pragma unroll
    for (int ni = 0; ni < 4; ni++)
      ctx[base + (size_t)row * H_DIM + ni * 16 + l16] = (bf16)(o[ni][r] * inv);
  }
}

// --------- fused reduce(2 partials) + residual + bias + LayerNorm over H=768 ----------
__global__ __launch_bounds__(256) void redln_k(const float* __restrict__ p0, const float* __restrict__ p1,
                                               const float* __restrict__ resF, const bf16* __restrict__ resB,
                                               const float* __restrict__ bias,
                                               const float* __restrict__ g, const float* __restrict__ bta,
                                               bf16* __restrict__ outB, float* __restrict__ outF) {
  int row = blockIdx.x, t = threadIdx.x;
  size_t base = (size_t)row * H_DIM;
  float v[3], s = 0.0f, sq = 0.0f;
#pragma unroll
  for (int i = 0; i < 3; i++) {
    int c = t + i * 256;
    float r = resF ? resF[base + c] : (float)resB[base + c];
    float x = p0[base + c] + p1[base + c] + bias[c] + r;
    v[i] = x; s += x; sq += x * x;
  }
#pragma unroll
  for (int off = 32; off >= 1; off >>= 1) { s += __shfl_down(s, off); sq += __shfl_down(sq, off); }
  __shared__ float ssum[4], ssq[4], smu, srs;
  int lane = t & 63, w = t >> 6;
  if (lane == 0) { ssum[w] = s; ssq[w] = sq; }
  __syncthreads();
  if (t == 0) {
    float S = ssum[0] + ssum[1] + ssum[2] + ssum[3];
    float Q = ssq[0] + ssq[1] + ssq[2] + ssq[3];
    float mu = S * (1.0f / H_DIM);
    float var = Q * (1.0f / H_DIM) - mu * mu;
    smu = mu;
    srs = rsqrtf(var + 1e-3f);
  }
  __syncthreads();
  float mu = smu, rs = srs;
#pragma unroll
  for (int i = 0; i < 3; i++) {
    int c = t + i * 256;
    float y = (v[i] - mu) * rs * g[c] + bta[c];
    if (outB) outB[base + c] = (bf16)y;
    if (outF) outF[base + c] = y;
  }
}

extern "C" void kernel_launch(void* const* d_in, const int* in_sizes, int n_in,
                              void* d_out, int out_size, void* d_ws, size_t ws_size,
                              hipStream_t stream) {
  const float* x    = (const float*)d_in[0];
  const int*   mask = (const int*)d_in[1];
  const float* Wq = (const float*)d_in[2];  const float* bq = (const float*)d_in[3];
  const float* Wk = (const float*)d_in[4];  const float* bk = (const float*)d_in[5];
  const float* Wv = (const float*)d_in[6];  const float* bv = (const float*)d_in[7];
  const float* Wo = (const float*)d_in[8];  const float* bo = (const float*)d_in[9];
  const float* ln1g = (const float*)d_in[10]; const float* ln1b = (const float*)d_in[11];
  const float* W1 = (const float*)d_in[12]; const float* b1 = (const float*)d_in[13];
  const float* W2 = (const float*)d_in[14]; const float* b2 = (const float*)d_in[15];
  const float* ln2g = (const float*)d_in[16]; const float* ln2b = (const float*)d_in[17];
  float* out = (float*)d_out;
  (void)ws_size; (void)in_sizes; (void)n_in; (void)out_size;

  // ---- workspace: exact lifetime aliasing, peak ~61.3 MB ----
  char* w = (char*)d_ws;
  const size_t SZ_TH  = 6291456;    // bf16 TOK x H
  const size_t SZ_THF = 12582912;   // fp32 TOK x H
  const size_t SZ_W   = 1179648;    // bf16 H x H
  bf16* xB   = (bf16*)(w);                        // dead after QKV
  bf16* QB   = (bf16*)(w + SZ_TH);                // dead after attn
  bf16* KB   = (bf16*)(w + 2 * SZ_TH);
  bf16* VB   = (bf16*)(w + 3 * SZ_TH);
  float* P1s0 = (float*)(w);                      // over xB+QB (dead)
  float* P1s1 = (float*)(w + SZ_THF);             // over KB+VB (dead)
  bf16* FFA  = (bf16*)(w);                        // over P1 (dead after redLN1)
  bf16* CTX  = (bf16*)(w + 4 * SZ_TH);            // dead after Wo-gemm
  bf16* H1   = CTX;                               // redLN1 out; alive till redLN2
  bf16* WqT  = (bf16*)(w + 5 * SZ_TH);            // dead after QKV
  bf16* WkT  = (bf16*)(w + 5 * SZ_TH + SZ_W);
  bf16* WvT  = (bf16*)(w + 5 * SZ_TH + 2 * SZ_W);
  bf16* WoT  = (bf16*)(w + 5 * SZ_TH + 3 * SZ_W); // dead after Wo-gemm
  bf16* W1T  = (bf16*)(w + 5 * SZ_TH + 4 * SZ_W); // dead after FF1
  float* P2s0 = (float*)(w + 5 * SZ_TH);          // over WqT..W1T (dead by FF2)
  float* P2s1 = (float*)(w + 5 * SZ_TH + SZ_THF);
  bf16* W2T  = (bf16*)(w + 5 * SZ_TH + 2 * SZ_THF); // alive till FF2-gemm

  dim3 tb(256);

  // conversions
  cvt_k<<<(TOK * H_DIM) / 2048, tb, 0, stream>>>(x, xB, TOK * H_DIM);
  CvtTArgs ct = {};
  ct.in[0] = Wq; ct.in[1] = Wk; ct.in[2] = Wv; ct.in[3] = Wo;
  ct.out[0] = WqT; ct.out[1] = WkT; ct.out[2] = WvT; ct.out[3] = WoT;
  cvtT_k<<<dim3(24, 24, 4), tb, 0, stream>>>(ct, H_DIM, H_DIM);
  CvtTArgs c1 = {}; c1.in[0] = W1; c1.out[0] = W1T;
  cvtT_k<<<dim3(96, 24, 1), tb, 0, stream>>>(c1, H_DIM, FF_DIM);
  CvtTArgs c2 = {}; c2.in[0] = W2; c2.out[0] = W2T;
  cvtT_k<<<dim3(24, 96, 1), tb, 0, stream>>>(c2, FF_DIM, H_DIM);

  // QKV: MODE 0, nx=12 (BN=64), grid 1152
  GemmArgs ga = {};
  ga.A = xB; ga.N = H_DIM; ga.K = H_DIM; ga.nx = 12; ga.ry = 4; ga.kSlices = 1;
  ga.W[0] = WqT; ga.W[1] = WkT; ga.W[2] = WvT;
  ga.bias[0] = bq; ga.bias[1] = bk; ga.bias[2] = bv;
  ga.outB[0] = QB; ga.outB[1] = KB; ga.outB[2] = VB;
  gemm_x<0><<<1152, tb, 0, stream>>>(ga);

  // attention
  attn_k<<<dim3(8 * NHEAD, SEQ / 64), tb, 0, stream>>>(QB, KB, VB, mask, CTX);

  // Wo-proj: MODE 2 split-K=2, grid 768
  GemmArgs go = {};
  go.A = CTX; go.N = H_DIM; go.K = H_DIM; go.nx = 12; go.ry = 4; go.kSlices = 2;
  go.W[0] = WoT; go.outP[0] = P1s0; go.outP[1] = P1s1;
  gemm_x<2><<<768, tb, 0, stream>>>(go);

  // reduce + residual(x) + bias(bo) + LN1 -> H1 (bf16)
  redln_k<<<TOK, tb, 0, stream>>>(P1s0, P1s1, x, nullptr, bo, ln1g, ln1b, H1, nullptr);

  // FF1 + GELU: MODE 1, nx=48, grid 1536
  GemmArgs g1 = {};
  g1.A = H1; g1.N = FF_DIM; g1.K = H_DIM; g1.nx = 48; g1.ry = 4; g1.kSlices = 1;
  g1.W[0] = W1T; g1.bias[0] = b1; g1.outB[0] = FFA;
  gemm_x<1><<<1536, tb, 0, stream>>>(g1);

  // FF2: MODE 2 split-K=2, grid 768
  GemmArgs g2 = {};
  g2.A = FFA; g2.N = H_DIM; g2.K = FF_DIM; g2.nx = 12; g2.ry = 4; g2.kSlices = 2;
  g2.W[0] = W2T; g2.outP[0] = P2s0; g2.outP[1] = P2s1;
  gemm_x<2><<<768, tb, 0, stream>>>(g2);

  // reduce + residual(H1 bf16) + bias(b2) + LN2 -> out (fp32)
  redln_k<<<TOK, tb, 0, stream>>>(P2s0, P2s1, nullptr, H1, b2, ln2g, ln2b, nullptr, out);
}